// Round 11
// baseline (117.948 us; speedup 1.0000x reference)
//
#include <hip/hip_runtime.h>
#include <hip/hip_bf16.h>

// MultiHeadAttention: x[2,2048,1024] fp32 -> QKV proj + RoPE + softmax attn + O proj
// R11: attn waves cover 64 q-rows each (f=4 Q-fragments share every K/V LDS read)
// -> per-CU LDS A-operand traffic halves. 256 q/block, grid=256 (1 block/CU),
// LDS 82KB, compile-time buffer schedule (R10), MFMA row-sum (R9).

#define SEQ    2048
#define BATCH  2
#define NHEADS 16
#define HDIM   64
#define HID    1024
#define NTOK   (BATCH*SEQ)   // 4096

typedef __bf16 bf16x8 __attribute__((ext_vector_type(8)));
typedef float  f32x4  __attribute__((ext_vector_type(4)));
typedef unsigned short u16x8 __attribute__((ext_vector_type(8)));

__device__ __forceinline__ unsigned short bfc(float x) {
  return __builtin_bit_cast(unsigned short, (__bf16)x);   // native v_cvt (RNE)
}
#define EXP2(x) __builtin_amdgcn_exp2f(x)

// async global->LDS, 16B per lane. dest = wave-uniform base (+ lane*16 by HW).
__device__ __forceinline__ void gload16(const void* gptr, void* ldsptr) {
  typedef __attribute__((address_space(3))) unsigned int as3_uint;
  typedef const __attribute__((address_space(1))) unsigned int as1_uint;
  __builtin_amdgcn_global_load_lds(
      (as1_uint*)(unsigned long long)gptr,
      (as3_uint*)(unsigned int)(unsigned long long)ldsptr,
      16, 0, 0);
}

__device__ __forceinline__ void cvt8(const float* __restrict__ s,
                                     unsigned short* __restrict__ d, int i) {
  float4 a = *reinterpret_cast<const float4*>(s + i);
  float4 b = *reinterpret_cast<const float4*>(s + i + 4);
  u16x8 o;
  o[0] = bfc(a.x); o[1] = bfc(a.y); o[2] = bfc(a.z); o[3] = bfc(a.w);
  o[4] = bfc(b.x); o[5] = bfc(b.y); o[6] = bfc(b.z); o[7] = bfc(b.w);
  *reinterpret_cast<u16x8*>(d + i) = o;
}

// ---------------- prep: all converts + rope tables in ONE launch ----------------
__global__ __launch_bounds__(256) void prep(
    const float* __restrict__ x,
    const float* __restrict__ qw, const float* __restrict__ kw,
    const float* __restrict__ vw, const float* __restrict__ ow,
    unsigned short* __restrict__ xb,
    unsigned short* __restrict__ wqb, unsigned short* __restrict__ wkb,
    unsigned short* __restrict__ wvb, unsigned short* __restrict__ wob,
    float* __restrict__ ct, float* __restrict__ st)
{
  const int XN = NTOK * HID / 8;   // 524288
  const int WN = HID * HID / 8;    // 131072 (pow2)
  int tid = blockIdx.x * 256 + threadIdx.x;
  if (tid < XN) {
    cvt8(x, xb, tid * 8);
  } else if (tid < XN + 4 * WN) {
    int r = tid - XN;
    int which = r >> 17;                 // / 131072
    int i = (r & (WN - 1)) * 8;
    const float* s = (which == 0) ? qw : (which == 1) ? kw : (which == 2) ? vw : ow;
    unsigned short* d = (which == 0) ? wqb : (which == 1) ? wkb : (which == 2) ? wvb : wob;
    cvt8(s, d, i);
  } else {
    int idx = tid - (XN + 4 * WN);
    if (idx < SEQ * 32) {
      int p = idx >> 5, j = idx & 31;
      float inv = powf(10000.0f, -(float)(2 * j) * (1.0f / 64.0f));
      float a = (float)p * inv;
      ct[idx] = cosf(a);
      st[idx] = sinf(a);
    }
  }
}

// ---------------- QKV GEMM (3-buf, counted vmcnt) + bias/RoPE epilogue; z==2 -> V^T ----------------
__global__ __launch_bounds__(256) void gemm_qkv(
    const unsigned short* __restrict__ X,
    const unsigned short* __restrict__ Wq, const unsigned short* __restrict__ Wk,
    const unsigned short* __restrict__ Wv,
    const float* __restrict__ bq, const float* __restrict__ bk, const float* __restrict__ bv,
    const float* __restrict__ ct, const float* __restrict__ st,
    unsigned short* __restrict__ Qo, unsigned short* __restrict__ Ko,
    unsigned short* __restrict__ VTo)   // V^T: [bh][d][s]
{
  __shared__ unsigned short LSH[24576];  // Al[3][4096] @0 | Bl[3][4096] @12288; T reuses first 16384
  const int z = blockIdx.z;
  const unsigned short* W = (z == 0) ? Wq : (z == 1) ? Wk : Wv;
  const float* bias = (z == 0) ? bq : (z == 1) ? bk : bv;
  const int tm = blockIdx.x, tn = blockIdx.y;
  const int t = threadIdx.x, w = t >> 6, l = t & 63;
  const int wm = w >> 1, wn = w & 1, g = l >> 4;

  f32x4 acc[4][4] = {};

  const int arow0 = tm * 128, brow0 = tn * 128;
  const int s0 = w * 2, s1 = w * 2 + 1;
  const int r0 = s0 * 16 + (l >> 2), r1 = s1 * 16 + (l >> 2);
  const int kc = (l & 3) * 8;

#define GSTAGE(buf, k0)                                                               \
  {                                                                                   \
    gload16(X + (long)(arow0 + r0) * HID + (k0) + kc, LSH + (buf) * 4096 + s0 * 512); \
    gload16(X + (long)(arow0 + r1) * HID + (k0) + kc, LSH + (buf) * 4096 + s1 * 512); \
    gload16(W + (long)(brow0 + r0) * HID + (k0) + kc, LSH + 12288 + (buf) * 4096 + s0 * 512); \
    gload16(W + (long)(brow0 + r1) * HID + (k0) + kc, LSH + 12288 + (buf) * 4096 + s1 * 512); \
  }

  GSTAGE(0, 0)
  GSTAGE(1, 32)
  asm volatile("s_waitcnt vmcnt(4)" ::: "memory");   // buf0 landed; buf1 in flight
  __builtin_amdgcn_s_barrier();
  int cur = 0, stg = 2;
  for (int k0 = 0; k0 < HID; k0 += 32) {
    if (k0 + 64 < HID) GSTAGE(stg, k0 + 64)
    bf16x8 af[4], bfr[4];
#pragma unroll
    for (int fm = 0; fm < 4; ++fm)
      af[fm] = *reinterpret_cast<const bf16x8*>(
          LSH + cur * 4096 + (wm * 64 + fm * 16 + (l & 15)) * 32 + g * 8);
#pragma unroll
    for (int fn = 0; fn < 4; ++fn)
      bfr[fn] = *reinterpret_cast<const bf16x8*>(
          LSH + 12288 + cur * 4096 + (wn * 64 + fn * 16 + (l & 15)) * 32 + g * 8);
    __builtin_amdgcn_s_setprio(1);
#pragma unroll
    for (int fm = 0; fm < 4; ++fm)
#pragma unroll
      for (int fn = 0; fn < 4; ++fn)
        acc[fm][fn] = __builtin_amdgcn_mfma_f32_16x16x32_bf16(af[fm], bfr[fn], acc[fm][fn], 0, 0, 0);
    __builtin_amdgcn_s_setprio(0);
    if (k0 + 64 < HID) {
      asm volatile("s_waitcnt vmcnt(4)" ::: "memory");   // next buf landed, newest stays in flight
    } else {
      asm volatile("s_waitcnt vmcnt(0)" ::: "memory");
    }
    __builtin_amdgcn_s_barrier();
    cur = (cur == 2) ? 0 : cur + 1;
    stg = (stg == 2) ? 0 : stg + 1;
  }
#undef GSTAGE

  const int colb = brow0 + wn * 64;
  float bsv[4];
#pragma unroll
  for (int fn = 0; fn < 4; ++fn) bsv[fn] = bias[colb + fn * 16 + (l & 15)];

  if (z == 2) {
    // ---- V^T epilogue: C-tile -> LDS transposed (XOR-swizzled) -> coalesced VT store
#pragma unroll
    for (int fm = 0; fm < 4; ++fm) {
      int tok = wm * 64 + fm * 16 + g * 4;
#pragma unroll
      for (int fn = 0; fn < 4; ++fn) {
        int col = wn * 64 + fn * 16 + (l & 15);
        unsigned int u0 = (unsigned int)bfc(acc[fm][fn][0] + bsv[fn]) |
                          ((unsigned int)bfc(acc[fm][fn][1] + bsv[fn]) << 16);
        unsigned int u1 = (unsigned int)bfc(acc[fm][fn][2] + bsv[fn]) |
                          ((unsigned int)bfc(acc[fm][fn][3] + bsv[fn]) << 16);
        uint2 uv; uv.x = u0; uv.y = u1;
        *reinterpret_cast<uint2*>(&LSH[col * 128 + (tok ^ ((col & 7) << 3))]) = uv;
      }
    }
    __syncthreads();
    const int bb = arow0 >> 11, stok = arow0 & (SEQ - 1);
#pragma unroll
    for (int p8 = 0; p8 < 8; ++p8) {
      int col = p8 * 16 + (t >> 4);          // 0..127
      int soff = (t & 15) * 8;
      uint4 v = *reinterpret_cast<const uint4*>(&LSH[col * 128 + (soff ^ ((col & 7) << 3))]);
      int hh = (brow0 + col) >> 6;
      int dd = col & 63;
      unsigned short* dst = VTo + ((long)(bb * NHEADS + hh) * HDIM + dd) * SEQ + stok + soff;
      *reinterpret_cast<uint4*>(dst) = v;
    }
    return;
  }

  // ---- Q/K epilogue: bias + RoPE (+0.125*log2e folded into Q), store [B][H][S][D]
  unsigned short* Out = (z == 0) ? Qo : Ko;
  const int h = colb >> 6;
#pragma unroll
  for (int fm = 0; fm < 4; ++fm) {
#pragma unroll
    for (int r = 0; r < 4; ++r) {
      int grow = arow0 + wm * 64 + fm * 16 + g * 4 + r;
      int b = grow >> 11, sidx = grow & (SEQ - 1);
      unsigned short* ob = Out + ((long)(b * NHEADS + h) * SEQ + sidx) * HDIM;
#pragma unroll
      for (int fn2 = 0; fn2 < 2; ++fn2) {
        int d1 = fn2 * 16 + (l & 15);               // 0..31
        float v1 = acc[fm][fn2][r] + bsv[fn2];
        float v2 = acc[fm][fn2 + 2][r] + bsv[fn2 + 2];
        float c = ct[sidx * 32 + d1], sn = st[sidx * 32 + d1];
        float o1 = v1 * c - v2 * sn;                // d
        float o2 = v2 * c + v1 * sn;                // d+32
        if (z == 0) { o1 *= 0.18033688f; o2 *= 0.18033688f; } // 0.125 * log2(e)
        ob[d1] = bfc(o1);
        ob[d1 + 32] = bfc(o2);
      }
    }
  }
}

// ---------------- flash attention R11: 64 q-rows per wave ----------------
// 4 waves x 64 q = 256 q/block; grid 256 = 1 block/CU. Every K/V LDS read
// feeds 4 Q-fragments -> per-CU LDS traffic ~halved vs R10. K dbuf, V 4-buf,
// 4x-unrolled compile-time schedule; MFMA row-sum via Vext ones-row.
__global__ __launch_bounds__(256, 1) void attn(
    const unsigned short* __restrict__ Qb,
    const unsigned short* __restrict__ Kb,
    const unsigned short* __restrict__ VTb,
    unsigned short* __restrict__ Ob)   // [NTOK][HID] bf16
{
  __shared__ unsigned short Kl[2][64 * 64];    // [key][d], swizzle ^((key&7)<<4)
  __shared__ unsigned short Vl[4][64 * 64];    // [d][key], swizzle ^((d&7)<<4)
  __shared__ unsigned short Pl[4][64 * 64];    // per-wave P [q][key], swizzled (8KB/wave)
  __shared__ unsigned short Vext[16 * 64];     // row0 = bf16(1.0), rows 1..15 = 0
  const int bh = blockIdx.x, qt = blockIdx.y;
  const int b = bh >> 4, h = bh & 15;
  const int t = threadIdx.x, w = t >> 6, l = t & 63;
  const long hb = (long)bh * SEQ * HDIM;
  const int g = l >> 4;
  const int swz = (l & 7) << 4;

  // Q as B-operand: frag f covers q = q0 + f*16 + (l&15); k = ks*32 + g*8 + j
  const int q0 = qt * 256 + w * 64;
  bf16x8 qf[4][2];
#pragma unroll
  for (int f = 0; f < 4; ++f)
#pragma unroll
    for (int ks = 0; ks < 2; ++ks)
      qf[f][ks] = *reinterpret_cast<const bf16x8*>(
          Qb + hb + (long)(q0 + f * 16 + (l & 15)) * HDIM + ks * 32 + g * 8);

  f32x4 oacc[4][4] = {};
  f32x4 oaccE[4] = {};           // row0 = per-q row-sum
  const f32x4 FZERO = {0.f, 0.f, 0.f, 0.f};

  // hoisted LDS read offsets (loop-invariant)
  const int rowq = (l & 15) * 128;                 // byte row offset (q / key / d row)
  const int colx0 = (g * 16) ^ swz;                // ks=0 col bytes
  const int colx1 = (64 + g * 16) ^ swz;           // ks=1 col bytes
  char* const Pw = (char*)Pl + w * 8192;

  // staging pointers (advance by one tile per STAGE)
  const int srow = l >> 3;
  const int scol = (((l & 7) * 16) ^ ((l >> 3) << 4)) >> 1;
  const unsigned short* kp0 = Kb + hb + (long)(w * 16 + srow) * HDIM + scol;
  const unsigned short* kp1 = kp0 + 8 * HDIM;
  const unsigned short* vp0 = VTb + hb + (long)(w * 16 + srow) * SEQ + scol;
  const unsigned short* vp1 = vp0 + 8 * SEQ;

#define STAGE(kbuf, vbuf)                                              \
  {                                                                    \
    gload16(kp0, (char*)Kl + (kbuf) * 8192 + w * 2048);                \
    gload16(kp1, (char*)Kl + (kbuf) * 8192 + w * 2048 + 1024);         \
    gload16(vp0, (char*)Vl + (vbuf) * 8192 + w * 2048);                \
    gload16(vp1, (char*)Vl + (vbuf) * 8192 + w * 2048 + 1024);         \
    kp0 += 64 * HDIM; kp1 += 64 * HDIM; vp0 += 64; vp1 += 64;          \
  }

#define QK(kbuf)                                                                  \
  _Pragma("unroll")                                                               \
  for (int fnK = 0; fnK < 4; ++fnK) {                                             \
    const char* kb_ = (char*)Kl + (kbuf) * 8192 + fnK * 2048 + rowq;              \
    bf16x8 kf0 = *reinterpret_cast<const bf16x8*>(kb_ + colx0);                   \
    bf16x8 kf1 = *reinterpret_cast<const bf16x8*>(kb_ + colx1);                   \
    _Pragma("unroll")                                                             \
    for (int f = 0; f < 4; ++f) {                                                 \
      sa[f][fnK] = __builtin_amdgcn_mfma_f32_16x16x32_bf16(kf0, qf[f][0], FZERO, 0, 0, 0); \
      sa[f][fnK] = __builtin_amdgcn_mfma_f32_16x16x32_bf16(kf1, qf[f][1], sa[f][fnK], 0, 0, 0); \
    }                                                                             \
  }

#define PFREAD                                                                    \
  _Pragma("unroll")                                                               \
  for (int f = 0; f < 4; ++f) {                                                   \
    pf[f][0] = *reinterpret_cast<const bf16x8*>(Pw + f * 2048 + rowq + colx0);    \
    pf[f][1] = *reinterpret_cast<const bf16x8*>(Pw + f * 2048 + rowq + colx1);    \
  }

#define PVSTEP(vbuf)                                                              \
  _Pragma("unroll")                                                               \
  for (int fnD = 0; fnD < 4; ++fnD) {                                             \
    const char* vb_ = (char*)Vl + (vbuf) * 8192 + fnD * 2048 + rowq;              \
    bf16x8 vf0 = *reinterpret_cast<const bf16x8*>(vb_ + colx0);                   \
    bf16x8 vf1 = *reinterpret_cast<const bf16x8*>(vb_ + colx1);                   \
    _Pragma("unroll")                                                             \
    for (int f = 0; f < 4; ++f) {                                                 \
      oacc[f][fnD] = __builtin_amdgcn_mfma_f32_16x16x32_bf16(vf0, pf[f][0], oacc[f][fnD], 0, 0, 0); \
      oacc[f][fnD] = __builtin_amdgcn_mfma_f32_16x16x32_bf16(vf1, pf[f][1], oacc[f][fnD], 0, 0, 0); \
    }                                                                             \
  }                                                                               \
  _Pragma("unroll")                                                               \
  for (int f = 0; f < 4; ++f) {                                                   \
    oaccE[f] = __builtin_amdgcn_mfma_f32_16x16x32_bf16(vxf0, pf[f][0], oaccE[f], 0, 0, 0); \
    oaccE[f] = __builtin_amdgcn_mfma_f32_16x16x32_bf16(vxf1, pf[f][1], oaccE[f], 0, 0, 0); \
  }

#define SOFTPACK                                                                  \
  _Pragma("unroll")                                                               \
  for (int f = 0; f < 4; ++f) {                                                   \
    _Pragma("unroll")                                                             \
    for (int fn = 0; fn < 4; ++fn)                                                \
      _Pragma("unroll")                                                           \
      for (int r = 0; r < 4; ++r) sa[f][fn][r] = EXP2(sa[f][fn][r]);              \
    char* pw_ = Pw + f * 2048 + rowq;                                             \
    _Pragma("unroll")                                                             \
    for (int fn = 0; fn < 4; ++fn) {                                              \
      unsigned int u0 = (unsigned int)bfc(sa[f][fn][0]) | ((unsigned int)bfc(sa[f][fn][1]) << 16); \
      unsigned int u1 = (unsigned int)bfc(sa[f][fn][2]) | ((unsigned int)bfc(sa[f][fn][3]) << 16); \
      uint2 uv; uv.x = u0; uv.y = u1;                                             \
      *reinterpret_cast<uint2*>(pw_ + ((fn * 32 + g * 8) ^ swz)) = uv;            \
    }                                                                             \
  }

// one pipelined iteration, all buffer indices compile-time
#define ITER(KB, VR, VW)                                   \
  {                                                        \
    PFREAD                                                 \
    STAGE(KB ^ 1, VW)                                      \
    __builtin_amdgcn_s_setprio(1);                         \
    QK(KB)                                                 \
    PVSTEP(VR)                                             \
    __builtin_amdgcn_s_setprio(0);                         \
    SOFTPACK                                               \
    asm volatile("s_waitcnt vmcnt(0)" ::: "memory");       \
    __builtin_amdgcn_s_barrier();                          \
  }
#define ITER_NOSTAGE(KB, VR)                               \
  {                                                        \
    PFREAD                                                 \
    __builtin_amdgcn_s_setprio(1);                         \
    QK(KB)                                                 \
    PVSTEP(VR)                                             \
    __builtin_amdgcn_s_setprio(0);                         \
    SOFTPACK                                               \
    asm volatile("s_waitcnt vmcnt(0)" ::: "memory");       \
    __builtin_amdgcn_s_barrier();                          \
  }

  f32x4 sa[4][4];
  bf16x8 pf[4][2];

  // init Vext: row0 = ones (linear; row0 swizzle = 0), rows 1..15 = 0
  {
    int i = t * 4;
#pragma unroll
    for (int j = 0; j < 4; ++j)
      Vext[i + j] = (i + j) < 64 ? (unsigned short)0x3F80 : (unsigned short)0;
  }

  // prologue: stage tile 0 into K[0],V[0]
  STAGE(0, 0)
  asm volatile("s_waitcnt vmcnt(0)" ::: "memory");
  __builtin_amdgcn_s_barrier();

  // Vext A-frags (static; same swizzle identity as K/V rows since (l&15)&7 == l&7)
  const bf16x8 vxf0 = *reinterpret_cast<const bf16x8*>((char*)Vext + rowq + colx0);
  const bf16x8 vxf1 = *reinterpret_cast<const bf16x8*>((char*)Vext + rowq + colx1);

  // peeled t=0: stage tile 1 -> K[1],V[1]; QK(0); softmax+pack(0); no PV yet
  STAGE(1, 1)
  __builtin_amdgcn_s_setprio(1);
  QK(0)
  __builtin_amdgcn_s_setprio(0);
  SOFTPACK
  asm volatile("s_waitcnt vmcnt(0)" ::: "memory");
  __builtin_amdgcn_s_barrier();

  // main: it = 1..28 in 7 unrolled groups of 4 (tile t=it; K[it&1], V read (it-1)&3, V write (it+1)&3)
  for (int m = 0; m < 7; ++m) {
    ITER(1, 0, 2)
    ITER(0, 1, 3)
    ITER(1, 2, 0)
    ITER(0, 3, 1)
  }
  ITER(1, 0, 2)        // it=29
  ITER(0, 1, 3)        // it=30
  ITER_NOSTAGE(1, 2)   // it=31 (last tile already staged)

  // epilogue: PV of tile 31 (P in Pl, V in Vl[3])
  PFREAD
  __builtin_amdgcn_s_setprio(1);
  PVSTEP(3)
  __builtin_amdgcn_s_setprio(0);

#undef STAGE
#undef QK
#undef PFREAD
#undef PVSTEP
#undef SOFTPACK
#undef ITER
#undef ITER_NOSTAGE

  // ---- normalize + store O (row-sum = oaccE[f][0] held by group-0 lanes)
#pragma unroll
  for (int f = 0; f < 4; ++f) {
    float lr = __shfl(oaccE[f][0], l & 15);    // broadcast D[row0][col=l&15]
    float inv = 1.0f / lr;
    int q = q0 + f * 16 + (l & 15);
    unsigned short* op = Ob + (long)(b * SEQ + q) * HID + h * HDIM;
#pragma unroll
    for (int fnD = 0; fnD < 4; ++fnD) {
      unsigned int lo = (unsigned int)bfc(oacc[f][fnD][0] * inv) |
                        ((unsigned int)bfc(oacc[f][fnD][1] * inv) << 16);
      unsigned int hi = (unsigned int)bfc(oacc[f][fnD][2] * inv) |
                        ((unsigned int)bfc(oacc[f][fnD][3] * inv) << 16);
      uint2 uv; uv.x = lo; uv.y = hi;
      *reinterpret_cast<uint2*>(op + fnD * 16 + g * 4) = uv;
    }
  }
}

// ---------------- output projection (3-buf counted vmcnt, 128x64 tile): fp32 out ----------------
__global__ __launch_bounds__(256) void gemm_o(
    const unsigned short* __restrict__ A,
    const unsigned short* __restrict__ W,
    const float* __restrict__ bias,
    float* __restrict__ Out)
{
  __shared__ unsigned short Al[3][128 * 32];
  __shared__ unsigned short Bl[3][64 * 32];
  const int tm = blockIdx.x, tn = blockIdx.y;
  const int t = threadIdx.x, w = t >> 6, l = t & 63;
  const int wm = w >> 1, wn = w & 1;

  f32x4 acc[4][2] = {};
  const int arow0 = tm * 128, brow0 = tn * 64;
  const int s0 = w * 2, s1 = w * 2 + 1;
  const int r0 = s0 * 16 + (l >> 2), r1 = s1 * 16 + (l >> 2);
  const int rb = w * 16 + (l >> 2);
  const int kc = (l & 3) * 8;

#define GSTAGE(buf, k0)                                                       \
  {                                                                           \
    gload16(A + (long)(arow0 + r0) * HID + (k0) + kc, Al[buf] + s0 * 512);    \
    gload16(A + (long)(arow0 + r1) * HID + (k0) + kc, Al[buf] + s1 * 512);    \
    gload16(W + (long)(brow0 + rb) * HID + (k0) + kc, Bl[buf] + w * 512);     \
  }

  GSTAGE(0, 0)
  GSTAGE(1, 32)
  asm volatile("s_waitcnt vmcnt(3)" ::: "memory");
  __builtin_amdgcn_s_barrier();
  int cur = 0, stg = 2;
  for (int k0 = 0; k0 < HID; k0 += 32) {
    if (k0 + 64 < HID) GSTAGE(stg, k0 + 64)
    bf16x8 af[4], bfr[2];
#pragma unroll
    for (int fm = 0; fm < 4; ++fm)
      af[fm] = *reinterpret_cast<const bf16x8*>(Al[cur] + (wm * 64 + fm * 16 + (l & 15)) * 32 + (l >> 4) * 8);
#pragma unroll
    for (int fn = 0; fn < 2; ++fn)
      bfr[fn] = *reinterpret_cast<const bf16x8*>(Bl[cur] + (wn * 32 + fn * 16 + (l & 15)) * 32 + (l >> 4) * 8);
    __builtin_amdgcn_s_setprio(1);
#pragma unroll
    for (int fm = 0; fm < 4; ++fm)
#pragma unroll
      for (int fn = 0; fn < 2; ++fn)
        acc[fm][fn] = __builtin_amdgcn_mfma_f32_16x16x32_bf16(af[fm], bfr[fn], acc[fm][fn], 0, 0, 0);
    __builtin_amdgcn_s_setprio(0);
    if (k0 + 64 < HID) {
      asm volatile("s_waitcnt vmcnt(3)" ::: "memory");
    } else {
      asm volatile("s_waitcnt vmcnt(0)" ::: "memory");
    }
    __builtin_amdgcn_s_barrier();
    cur = (cur == 2) ? 0 : cur + 1;
    stg = (stg == 2) ? 0 : stg + 1;
  }
#undef GSTAGE

  const int colb = brow0 + wn * 32;
  float bsv[2];
#pragma unroll
  for (int fn = 0; fn < 2; ++fn) bsv[fn] = bias[colb + fn * 16 + (l & 15)];
#pragma unroll
  for (int fm = 0; fm < 4; ++fm)
#pragma unroll
    for (int r = 0; r < 4; ++r) {
      int grow = arow0 + wm * 64 + fm * 16 + (l >> 4) * 4 + r;
#pragma unroll
      for (int fn = 0; fn < 2; ++fn)
        Out[(long)grow * HID + colb + fn * 16 + (l & 15)] = acc[fm][fn][r] + bsv[fn];
    }
}

extern "C" void kernel_launch(void* const* d_in, const int* in_sizes, int n_in,
                              void* d_out, int out_size, void* d_ws, size_t ws_size,
                              hipStream_t stream) {
  const float* x  = (const float*)d_in[0];
  const float* qw = (const float*)d_in[1];
  const float* qb = (const float*)d_in[2];
  const float* kw = (const float*)d_in[3];
  const float* kb = (const float*)d_in[4];
  const float* vw = (const float*)d_in[5];
  const float* vb = (const float*)d_in[6];
  const float* ow = (const float*)d_in[7];
  const float* ob = (const float*)d_in[8];
  float* out = (float*)d_out;

  char* p = (char*)d_ws;
  unsigned short* xb  = (unsigned short*)p; p += (size_t)NTOK * HID * 2;
  unsigned short* wqb = (unsigned short*)p; p += (size_t)HID * HID * 2;
  unsigned short* wkb = (unsigned short*)p; p += (size_t)HID * HID * 2;
  unsigned short* wvb = (unsigned short*)p; p += (size_t)HID * HID * 2;
  unsigned short* wob = (unsigned short*)p; p += (size_t)HID * HID * 2;
  unsigned short* Qb  = (unsigned short*)p; p += (size_t)NTOK * HID * 2;
  unsigned short* Kb  = (unsigned short*)p; p += (size_t)NTOK * HID * 2;
  unsigned short* VTb = (unsigned short*)p; p += (size_t)NTOK * HID * 2;
  float* ct = (float*)p; p += (size_t)SEQ * 32 * 4;
  float* st = (float*)p; p += (size_t)SEQ * 32 * 4;
  unsigned short* Ab  = xb;   // xb dead after gemm_qkv; reuse for attn output

  const int XN = NTOK * HID / 8, WN = HID * HID / 8;
  const int prep_threads = XN + 4 * WN + SEQ * 32;
  prep<<<dim3((prep_threads + 255) / 256), 256, 0, stream>>>(
      x, qw, kw, vw, ow, xb, wqb, wkb, wvb, wob, ct, st);

  gemm_qkv<<<dim3(NTOK / 128, HID / 128, 3), 256, 0, stream>>>(
      xb, wqb, wkb, wvb, qb, kb, vb, ct, st, Qb, Kb, VTb);

  attn<<<dim3(BATCH * NHEADS, SEQ / 256), 256, 0, stream>>>(Qb, Kb, VTb, Ab);

  gemm_o<<<dim3(NTOK / 128, HID / 64), 256, 0, stream>>>(Ab, wob, ob, out);
}

// Round 12
// 114.893 us; speedup vs baseline: 1.0266x; 1.0266x over previous
//
#include <hip/hip_runtime.h>
#include <hip/hip_bf16.h>

// MultiHeadAttention: x[2,2048,1024] fp32 -> QKV proj + RoPE + softmax attn + O proj
// R12: attn on 32x32x16 MFMA, swapped operands. P stays IN REGISTERS via
// cvt-pack + v_permlane32_swap_b32 (T12); row-sum via ones-A MFMA. No P LDS,
// no Vext. 32 q/wave (R10 geometry: 2 blocks/CU, 2 waves/SIMD), LDS 48KB.

#define SEQ    2048
#define BATCH  2
#define NHEADS 16
#define HDIM   64
#define HID    1024
#define NTOK   (BATCH*SEQ)   // 4096

typedef __bf16 bf16x8 __attribute__((ext_vector_type(8)));
typedef float  f32x4  __attribute__((ext_vector_type(4)));
typedef float  f32x16 __attribute__((ext_vector_type(16)));
typedef unsigned short u16x8 __attribute__((ext_vector_type(8)));
typedef unsigned int   u32x4 __attribute__((ext_vector_type(4)));

__device__ __forceinline__ unsigned short bfc(float x) {
  return __builtin_bit_cast(unsigned short, (__bf16)x);   // native v_cvt (RNE)
}
__device__ __forceinline__ unsigned int pk(float lo, float hi) {
  return (unsigned int)bfc(lo) | ((unsigned int)bfc(hi) << 16);
}
// swap upper 32 lanes of a with lower 32 lanes of b (gfx950)
__device__ __forceinline__ void plswap(unsigned int& a, unsigned int& b) {
  asm volatile("v_permlane32_swap_b32 %0, %1" : "+v"(a), "+v"(b));
}
#define EXP2(x) __builtin_amdgcn_exp2f(x)
#define MFMA32(a, b, c) __builtin_amdgcn_mfma_f32_32x32x16_bf16(a, b, c, 0, 0, 0)

// async global->LDS, 16B per lane. dest = wave-uniform base (+ lane*16 by HW).
__device__ __forceinline__ void gload16(const void* gptr, void* ldsptr) {
  typedef __attribute__((address_space(3))) unsigned int as3_uint;
  typedef const __attribute__((address_space(1))) unsigned int as1_uint;
  __builtin_amdgcn_global_load_lds(
      (as1_uint*)(unsigned long long)gptr,
      (as3_uint*)(unsigned int)(unsigned long long)ldsptr,
      16, 0, 0);
}

__device__ __forceinline__ void cvt8(const float* __restrict__ s,
                                     unsigned short* __restrict__ d, int i) {
  float4 a = *reinterpret_cast<const float4*>(s + i);
  float4 b = *reinterpret_cast<const float4*>(s + i + 4);
  u16x8 o;
  o[0] = bfc(a.x); o[1] = bfc(a.y); o[2] = bfc(a.z); o[3] = bfc(a.w);
  o[4] = bfc(b.x); o[5] = bfc(b.y); o[6] = bfc(b.z); o[7] = bfc(b.w);
  *reinterpret_cast<u16x8*>(d + i) = o;
}

// ---------------- prep: all converts + rope tables in ONE launch ----------------
__global__ __launch_bounds__(256) void prep(
    const float* __restrict__ x,
    const float* __restrict__ qw, const float* __restrict__ kw,
    const float* __restrict__ vw, const float* __restrict__ ow,
    unsigned short* __restrict__ xb,
    unsigned short* __restrict__ wqb, unsigned short* __restrict__ wkb,
    unsigned short* __restrict__ wvb, unsigned short* __restrict__ wob,
    float* __restrict__ ct, float* __restrict__ st)
{
  const int XN = NTOK * HID / 8;   // 524288
  const int WN = HID * HID / 8;    // 131072 (pow2)
  int tid = blockIdx.x * 256 + threadIdx.x;
  if (tid < XN) {
    cvt8(x, xb, tid * 8);
  } else if (tid < XN + 4 * WN) {
    int r = tid - XN;
    int which = r >> 17;                 // / 131072
    int i = (r & (WN - 1)) * 8;
    const float* s = (which == 0) ? qw : (which == 1) ? kw : (which == 2) ? vw : ow;
    unsigned short* d = (which == 0) ? wqb : (which == 1) ? wkb : (which == 2) ? wvb : wob;
    cvt8(s, d, i);
  } else {
    int idx = tid - (XN + 4 * WN);
    if (idx < SEQ * 32) {
      int p = idx >> 5, j = idx & 31;
      float inv = powf(10000.0f, -(float)(2 * j) * (1.0f / 64.0f));
      float a = (float)p * inv;
      ct[idx] = cosf(a);
      st[idx] = sinf(a);
    }
  }
}

// ---------------- QKV GEMM (3-buf, counted vmcnt) + bias/RoPE epilogue; z==2 -> V^T ----------------
__global__ __launch_bounds__(256) void gemm_qkv(
    const unsigned short* __restrict__ X,
    const unsigned short* __restrict__ Wq, const unsigned short* __restrict__ Wk,
    const unsigned short* __restrict__ Wv,
    const float* __restrict__ bq, const float* __restrict__ bk, const float* __restrict__ bv,
    const float* __restrict__ ct, const float* __restrict__ st,
    unsigned short* __restrict__ Qo, unsigned short* __restrict__ Ko,
    unsigned short* __restrict__ VTo)   // V^T: [bh][d][s]
{
  __shared__ unsigned short LSH[24576];  // Al[3][4096] @0 | Bl[3][4096] @12288; T reuses first 16384
  const int z = blockIdx.z;
  const unsigned short* W = (z == 0) ? Wq : (z == 1) ? Wk : Wv;
  const float* bias = (z == 0) ? bq : (z == 1) ? bk : bv;
  const int tm = blockIdx.x, tn = blockIdx.y;
  const int t = threadIdx.x, w = t >> 6, l = t & 63;
  const int wm = w >> 1, wn = w & 1, g = l >> 4;

  f32x4 acc[4][4] = {};

  const int arow0 = tm * 128, brow0 = tn * 128;
  const int s0 = w * 2, s1 = w * 2 + 1;
  const int r0 = s0 * 16 + (l >> 2), r1 = s1 * 16 + (l >> 2);
  const int kc = (l & 3) * 8;

#define GSTAGE(buf, k0)                                                               \
  {                                                                                   \
    gload16(X + (long)(arow0 + r0) * HID + (k0) + kc, LSH + (buf) * 4096 + s0 * 512); \
    gload16(X + (long)(arow0 + r1) * HID + (k0) + kc, LSH + (buf) * 4096 + s1 * 512); \
    gload16(W + (long)(brow0 + r0) * HID + (k0) + kc, LSH + 12288 + (buf) * 4096 + s0 * 512); \
    gload16(W + (long)(brow0 + r1) * HID + (k0) + kc, LSH + 12288 + (buf) * 4096 + s1 * 512); \
  }

  GSTAGE(0, 0)
  GSTAGE(1, 32)
  asm volatile("s_waitcnt vmcnt(4)" ::: "memory");   // buf0 landed; buf1 in flight
  __builtin_amdgcn_s_barrier();
  int cur = 0, stg = 2;
  for (int k0 = 0; k0 < HID; k0 += 32) {
    if (k0 + 64 < HID) GSTAGE(stg, k0 + 64)
    bf16x8 af[4], bfr[4];
#pragma unroll
    for (int fm = 0; fm < 4; ++fm)
      af[fm] = *reinterpret_cast<const bf16x8*>(
          LSH + cur * 4096 + (wm * 64 + fm * 16 + (l & 15)) * 32 + g * 8);
#pragma unroll
    for (int fn = 0; fn < 4; ++fn)
      bfr[fn] = *reinterpret_cast<const bf16x8*>(
          LSH + 12288 + cur * 4096 + (wn * 64 + fn * 16 + (l & 15)) * 32 + g * 8);
    __builtin_amdgcn_s_setprio(1);
#pragma unroll
    for (int fm = 0; fm < 4; ++fm)
#pragma unroll
      for (int fn = 0; fn < 4; ++fn)
        acc[fm][fn] = __builtin_amdgcn_mfma_f32_16x16x32_bf16(af[fm], bfr[fn], acc[fm][fn], 0, 0, 0);
    __builtin_amdgcn_s_setprio(0);
    if (k0 + 64 < HID) {
      asm volatile("s_waitcnt vmcnt(4)" ::: "memory");   // next buf landed, newest stays in flight
    } else {
      asm volatile("s_waitcnt vmcnt(0)" ::: "memory");
    }
    __builtin_amdgcn_s_barrier();
    cur = (cur == 2) ? 0 : cur + 1;
    stg = (stg == 2) ? 0 : stg + 1;
  }
#undef GSTAGE

  const int colb = brow0 + wn * 64;
  float bsv[4];
#pragma unroll
  for (int fn = 0; fn < 4; ++fn) bsv[fn] = bias[colb + fn * 16 + (l & 15)];

  if (z == 2) {
    // ---- V^T epilogue: C-tile -> LDS transposed (XOR-swizzled) -> coalesced VT store
#pragma unroll
    for (int fm = 0; fm < 4; ++fm) {
      int tok = wm * 64 + fm * 16 + g * 4;
#pragma unroll
      for (int fn = 0; fn < 4; ++fn) {
        int col = wn * 64 + fn * 16 + (l & 15);
        unsigned int u0 = (unsigned int)bfc(acc[fm][fn][0] + bsv[fn]) |
                          ((unsigned int)bfc(acc[fm][fn][1] + bsv[fn]) << 16);
        unsigned int u1 = (unsigned int)bfc(acc[fm][fn][2] + bsv[fn]) |
                          ((unsigned int)bfc(acc[fm][fn][3] + bsv[fn]) << 16);
        uint2 uv; uv.x = u0; uv.y = u1;
        *reinterpret_cast<uint2*>(&LSH[col * 128 + (tok ^ ((col & 7) << 3))]) = uv;
      }
    }
    __syncthreads();
    const int bb = arow0 >> 11, stok = arow0 & (SEQ - 1);
#pragma unroll
    for (int p8 = 0; p8 < 8; ++p8) {
      int col = p8 * 16 + (t >> 4);          // 0..127
      int soff = (t & 15) * 8;
      uint4 v = *reinterpret_cast<const uint4*>(&LSH[col * 128 + (soff ^ ((col & 7) << 3))]);
      int hh = (brow0 + col) >> 6;
      int dd = col & 63;
      unsigned short* dst = VTo + ((long)(bb * NHEADS + hh) * HDIM + dd) * SEQ + stok + soff;
      *reinterpret_cast<uint4*>(dst) = v;
    }
    return;
  }

  // ---- Q/K epilogue: bias + RoPE (+0.125*log2e folded into Q), store [B][H][S][D]
  unsigned short* Out = (z == 0) ? Qo : Ko;
  const int h = colb >> 6;
#pragma unroll
  for (int fm = 0; fm < 4; ++fm) {
#pragma unroll
    for (int r = 0; r < 4; ++r) {
      int grow = arow0 + wm * 64 + fm * 16 + g * 4 + r;
      int b = grow >> 11, sidx = grow & (SEQ - 1);
      unsigned short* ob = Out + ((long)(b * NHEADS + h) * SEQ + sidx) * HDIM;
#pragma unroll
      for (int fn2 = 0; fn2 < 2; ++fn2) {
        int d1 = fn2 * 16 + (l & 15);               // 0..31
        float v1 = acc[fm][fn2][r] + bsv[fn2];
        float v2 = acc[fm][fn2 + 2][r] + bsv[fn2 + 2];
        float c = ct[sidx * 32 + d1], sn = st[sidx * 32 + d1];
        float o1 = v1 * c - v2 * sn;                // d
        float o2 = v2 * c + v1 * sn;                // d+32
        if (z == 0) { o1 *= 0.18033688f; o2 *= 0.18033688f; } // 0.125 * log2(e)
        ob[d1] = bfc(o1);
        ob[d1 + 32] = bfc(o2);
      }
    }
  }
}

// ---------------- flash attention R12: 32x32 MFMA, in-register P ----------------
// 4 waves x 32 q; KVBLK=64; swapped QK^T on mfma_32x32x16:
//   S^T C-layout: col=l&31 (q), row(key) = (r&3)+8*(r>>2)+4*(l>>5)+32*blk.
// PV B-frag (keys 16kc+8h+j) built in-register: pack pairs + permlane32_swap.
// Row-sum: ones-A MFMA -> every lane's reg0 = sum for its own q.
__global__ __launch_bounds__(256) void attn(
    const unsigned short* __restrict__ Qb,
    const unsigned short* __restrict__ Kb,
    const unsigned short* __restrict__ VTb,
    unsigned short* __restrict__ Ob)   // [NTOK][HID] bf16
{
  __shared__ unsigned short Kl[2][64 * 64];    // [key][d], swizzle ^((key&7)<<4)
  __shared__ unsigned short Vl[4][64 * 64];    // [d][key], swizzle ^((d&7)<<4)
  const int bh = blockIdx.x, qt = blockIdx.y;
  const int b = bh >> 4, h = bh & 15;
  const int t = threadIdx.x, w = t >> 6, l = t & 63;
  const long hb = (long)bh * SEQ * HDIM;
  const int hh = l >> 5;          // half-wave index
  const int swz = (l & 7) << 4;   // byte swizzle for row-reads (row&7 == l&7)

  // Q as B-operand: col=l&31 (q), k(d) = dc*16 + hh*8 + j
  const int q0 = qt * 128 + w * 32;
  bf16x8 qf[4];
#pragma unroll
  for (int dc = 0; dc < 4; ++dc)
    qf[dc] = *reinterpret_cast<const bf16x8*>(
        Qb + hb + (long)(q0 + (l & 31)) * HDIM + dc * 16 + hh * 8);

  f32x16 oacc[2] = {};           // O^T d-blocks; col=q=l&31
  f32x16 oaccE = {};             // every reg = row-sum of P for q=l&31
  const f32x16 FZ16 = {};

  // ones A-fragment (bf16 1.0 x8)
  u32x4 ou; ou[0] = 0x3F803F80u; ou[1] = 0x3F803F80u; ou[2] = 0x3F803F80u; ou[3] = 0x3F803F80u;
  const bf16x8 ones8 = __builtin_bit_cast(bf16x8, ou);

  // staging pointers (advance by one tile per STAGE) -- identical to R10
  const int srow = l >> 3;
  const int scol = (((l & 7) * 16) ^ ((l >> 3) << 4)) >> 1;
  const unsigned short* kp0 = Kb + hb + (long)(w * 16 + srow) * HDIM + scol;
  const unsigned short* kp1 = kp0 + 8 * HDIM;
  const unsigned short* vp0 = VTb + hb + (long)(w * 16 + srow) * SEQ + scol;
  const unsigned short* vp1 = vp0 + 8 * SEQ;

#define STAGE(kbuf, vbuf)                                              \
  {                                                                    \
    gload16(kp0, (char*)Kl + (kbuf) * 8192 + w * 2048);                \
    gload16(kp1, (char*)Kl + (kbuf) * 8192 + w * 2048 + 1024);         \
    gload16(vp0, (char*)Vl + (vbuf) * 8192 + w * 2048);                \
    gload16(vp1, (char*)Vl + (vbuf) * 8192 + w * 2048 + 1024);         \
    kp0 += 64 * HDIM; kp1 += 64 * HDIM; vp0 += 64; vp1 += 64;          \
  }

// S^T = K Q : sa[blk] covers keys 32blk..32blk+31 for this wave's 32 q
#define QK(kbuf)                                                                  \
  _Pragma("unroll")                                                               \
  for (int blk = 0; blk < 2; ++blk) {                                             \
    const char* kb_ = (char*)Kl + (kbuf) * 8192 + (32 * blk + (l & 31)) * 128;    \
    bf16x8 kf0 = *reinterpret_cast<const bf16x8*>(kb_ + ((0 * 32 + hh * 16) ^ swz)); \
    sa[blk] = MFMA32(kf0, qf[0], FZ16);                                           \
    bf16x8 kf1 = *reinterpret_cast<const bf16x8*>(kb_ + ((1 * 32 + hh * 16) ^ swz)); \
    sa[blk] = MFMA32(kf1, qf[1], sa[blk]);                                        \
    bf16x8 kf2 = *reinterpret_cast<const bf16x8*>(kb_ + ((2 * 32 + hh * 16) ^ swz)); \
    sa[blk] = MFMA32(kf2, qf[2], sa[blk]);                                        \
    bf16x8 kf3 = *reinterpret_cast<const bf16x8*>(kb_ + ((3 * 32 + hh * 16) ^ swz)); \
    sa[blk] = MFMA32(kf3, qf[3], sa[blk]);                                        \
  }

#define SOFTEXP                                                                   \
  _Pragma("unroll")                                                               \
  for (int blk = 0; blk < 2; ++blk)                                               \
    _Pragma("unroll")                                                             \
    for (int r = 0; r < 16; ++r) sa[blk][r] = EXP2(sa[blk][r]);

// build PV B-frags in-register: PB[2blk+kc'] = keys 16(2blk+kc')+8h+{0..7} for q=l&31
#define PBUILD(PB)                                                                \
  _Pragma("unroll")                                                               \
  for (int blk = 0; blk < 2; ++blk) {                                             \
    unsigned int w0a = pk(sa[blk][0], sa[blk][1]);                                \
    unsigned int w1a = pk(sa[blk][2], sa[blk][3]);                                \
    unsigned int w0b = pk(sa[blk][4], sa[blk][5]);                                \
    unsigned int w1b = pk(sa[blk][6], sa[blk][7]);                                \
    unsigned int w0c = pk(sa[blk][8], sa[blk][9]);                                \
    unsigned int w1c = pk(sa[blk][10], sa[blk][11]);                              \
    unsigned int w0d = pk(sa[blk][12], sa[blk][13]);                              \
    unsigned int w1d = pk(sa[blk][14], sa[blk][15]);                              \
    plswap(w0a, w0b); plswap(w1a, w1b);                                           \
    plswap(w0c, w0d); plswap(w1c, w1d);                                           \
    u32x4 f0; f0[0] = w0a; f0[1] = w1a; f0[2] = w0b; f0[3] = w1b;                 \
    u32x4 f1; f1[0] = w0c; f1[1] = w1c; f1[2] = w0d; f1[3] = w1d;                 \
    PB[2 * blk + 0] = __builtin_bit_cast(bf16x8, f0);                             \
    PB[2 * blk + 1] = __builtin_bit_cast(bf16x8, f1);                             \
  }

// O^T += V^T P ; oaccE += 1*P (row-sum)
#define PVSTEP(vbuf, PB)                                                          \
  _Pragma("unroll")                                                               \
  for (int db = 0; db < 2; ++db) {                                                \
    const char* vb_ = (char*)Vl + (vbuf) * 8192 + (32 * db + (l & 31)) * 128;     \
    _Pragma("unroll")                                                             \
    for (int kc = 0; kc < 4; ++kc) {                                              \
      bf16x8 vf = *reinterpret_cast<const bf16x8*>(vb_ + ((kc * 32 + hh * 16) ^ swz)); \
      oacc[db] = MFMA32(vf, PB[kc], oacc[db]);                                    \
    }                                                                             \
  }                                                                               \
  _Pragma("unroll")                                                               \
  for (int kc = 0; kc < 4; ++kc) oaccE = MFMA32(ones8, PB[kc], oaccE);

#define ITER(KB, VR, VW, PPREV, PNXT)                      \
  {                                                        \
    STAGE(KB ^ 1, VW)                                      \
    __builtin_amdgcn_s_setprio(1);                         \
    QK(KB)                                                 \
    PVSTEP(VR, PPREV)                                      \
    __builtin_amdgcn_s_setprio(0);                         \
    SOFTEXP                                                \
    PBUILD(PNXT)                                           \
    asm volatile("s_waitcnt vmcnt(0)" ::: "memory");       \
    __builtin_amdgcn_s_barrier();                          \
  }
#define ITER_NOSTAGE(KB, VR, PPREV, PNXT)                  \
  {                                                        \
    __builtin_amdgcn_s_setprio(1);                         \
    QK(KB)                                                 \
    PVSTEP(VR, PPREV)                                      \
    __builtin_amdgcn_s_setprio(0);                         \
    SOFTEXP                                                \
    PBUILD(PNXT)                                           \
    asm volatile("s_waitcnt vmcnt(0)" ::: "memory");       \
    __builtin_amdgcn_s_barrier();                          \
  }

  f32x16 sa[2];
  bf16x8 pBa[4], pBb[4];

  // prologue: stage tile 0 into K[0],V[0]
  STAGE(0, 0)
  asm volatile("s_waitcnt vmcnt(0)" ::: "memory");
  __builtin_amdgcn_s_barrier();

  // peeled t=0: stage tile 1; QK(0); exp2+PBUILD -> pBa; no PV yet
  STAGE(1, 1)
  __builtin_amdgcn_s_setprio(1);
  QK(0)
  __builtin_amdgcn_s_setprio(0);
  SOFTEXP
  PBUILD(pBa)
  asm volatile("s_waitcnt vmcnt(0)" ::: "memory");
  __builtin_amdgcn_s_barrier();

  // main: t = 1..28 in 7 unrolled groups of 4; P alternates pBa/pBb
  for (int m = 0; m < 7; ++m) {
    ITER(1, 0, 2, pBa, pBb)
    ITER(0, 1, 3, pBb, pBa)
    ITER(1, 2, 0, pBa, pBb)
    ITER(0, 3, 1, pBb, pBa)
  }
  ITER(1, 0, 2, pBa, pBb)          // t=29
  ITER(0, 1, 3, pBb, pBa)          // t=30
  ITER_NOSTAGE(1, 2, pBa, pBb)     // t=31 (already staged)

  // epilogue: PV of tile 31 (P in pBb, V in Vl[3])
  __builtin_amdgcn_s_setprio(1);
  PVSTEP(3, pBb)
  __builtin_amdgcn_s_setprio(0);

#undef STAGE
#undef QK
#undef SOFTEXP
#undef PBUILD
#undef PVSTEP
#undef ITER
#undef ITER_NOSTAGE

  // ---- normalize + store O^T (lane owns q = q0+(l&31); d = (r&3)+8(r>>2)+4hh+32db)
  {
    float inv = 1.0f / oaccE[0];
    int q = q0 + (l & 31);
    unsigned short* op = Ob + (long)(b * SEQ + q) * HID + h * HDIM;
#pragma unroll
    for (int db = 0; db < 2; ++db)
#pragma unroll
      for (int a = 0; a < 4; ++a) {
        int d = 8 * a + 4 * hh + 32 * db;
        unsigned int lo = pk(oacc[db][4 * a + 0] * inv, oacc[db][4 * a + 1] * inv);
        unsigned int hi2 = pk(oacc[db][4 * a + 2] * inv, oacc[db][4 * a + 3] * inv);
        uint2 uv; uv.x = lo; uv.y = hi2;
        *reinterpret_cast<uint2*>(op + d) = uv;
      }
  }
}

// ---------------- output projection (3-buf counted vmcnt, 128x64 tile): fp32 out ----------------
__global__ __launch_bounds__(256) void gemm_o(
    const unsigned short* __restrict__ A,
    const unsigned short* __restrict__ W,
    const float* __restrict__ bias,
    float* __restrict__ Out)
{
  __shared__ unsigned short Al[3][128 * 32];
  __shared__ unsigned short Bl[3][64 * 32];
  const int tm = blockIdx.x, tn = blockIdx.y;
  const int t = threadIdx.x, w = t >> 6, l = t & 63;
  const int wm = w >> 1, wn = w & 1;

  f32x4 acc[4][2] = {};
  const int arow0 = tm * 128, brow0 = tn * 64;
  const int s0 = w * 2, s1 = w * 2 + 1;
  const int r0 = s0 * 16 + (l >> 2), r1 = s1 * 16 + (l >> 2);
  const int rb = w * 16 + (l >> 2);
  const int kc = (l & 3) * 8;

#define GSTAGE(buf, k0)                                                       \
  {                                                                           \
    gload16(A + (long)(arow0 + r0) * HID + (k0) + kc, Al[buf] + s0 * 512);    \
    gload16(A + (long)(arow0 + r1) * HID + (k0) + kc, Al[buf] + s1 * 512);    \
    gload16(W + (long)(brow0 + rb) * HID + (k0) + kc, Bl[buf] + w * 512);     \
  }

  GSTAGE(0, 0)
  GSTAGE(1, 32)
  asm volatile("s_waitcnt vmcnt(3)" ::: "memory");
  __builtin_amdgcn_s_barrier();
  int cur = 0, stg = 2;
  for (int k0 = 0; k0 < HID; k0 += 32) {
    if (k0 + 64 < HID) GSTAGE(stg, k0 + 64)
    bf16x8 af[4], bfr[2];
#pragma unroll
    for (int fm = 0; fm < 4; ++fm)
      af[fm] = *reinterpret_cast<const bf16x8*>(Al[cur] + (wm * 64 + fm * 16 + (l & 15)) * 32 + (l >> 4) * 8);
#pragma unroll
    for (int fn = 0; fn < 2; ++fn)
      bfr[fn] = *reinterpret_cast<const bf16x8*>(Bl[cur] + (wn * 32 + fn * 16 + (l & 15)) * 32 + (l >> 4) * 8);
    __builtin_amdgcn_s_setprio(1);
#pragma unroll
    for (int fm = 0; fm < 4; ++fm)
#pragma unroll
      for (int fn = 0; fn < 2; ++fn)
        acc[fm][fn] = __builtin_amdgcn_mfma_f32_16x16x32_bf16(af[fm], bfr[fn], acc[fm][fn], 0, 0, 0);
    __builtin_amdgcn_s_setprio(0);
    if (k0 + 64 < HID) {
      asm volatile("s_waitcnt vmcnt(3)" ::: "memory");
    } else {
      asm volatile("s_waitcnt vmcnt(0)" ::: "memory");
    }
    __builtin_amdgcn_s_barrier();
    cur = (cur == 2) ? 0 : cur + 1;
    stg = (stg == 2) ? 0 : stg + 1;
  }
#undef GSTAGE

  const int colb = brow0 + wn * 32;
  float bsv[2];
#pragma unroll
  for (int fn = 0; fn < 2; ++fn) bsv[fn] = bias[colb + fn * 16 + (l & 15)];
#pragma unroll
  for (int fm = 0; fm < 4; ++fm)
#pragma unroll
    for (int r = 0; r < 4; ++r) {
      int grow = arow0 + wm * 64 + fm * 16 + (l >> 4) * 4 + r;
#pragma unroll
      for (int fn = 0; fn < 2; ++fn)
        Out[(long)grow * HID + colb + fn * 16 + (l & 15)] = acc[fm][fn][r] + bsv[fn];
    }
}

extern "C" void kernel_launch(void* const* d_in, const int* in_sizes, int n_in,
                              void* d_out, int out_size, void* d_ws, size_t ws_size,
                              hipStream_t stream) {
  const float* x  = (const float*)d_in[0];
  const float* qw = (const float*)d_in[1];
  const float* qb = (const float*)d_in[2];
  const float* kw = (const float*)d_in[3];
  const float* kb = (const float*)d_in[4];
  const float* vw = (const float*)d_in[5];
  const float* vb = (const float*)d_in[6];
  const float* ow = (const float*)d_in[7];
  const float* ob = (const float*)d_in[8];
  float* out = (float*)d_out;

  char* p = (char*)d_ws;
  unsigned short* xb  = (unsigned short*)p; p += (size_t)NTOK * HID * 2;
  unsigned short* wqb = (unsigned short*)p; p += (size_t)HID * HID * 2;
  unsigned short* wkb = (unsigned short*)p; p += (size_t)HID * HID * 2;
  unsigned short* wvb = (unsigned short*)p; p += (size_t)HID * HID * 2;
  unsigned short* wob = (unsigned short*)p; p += (size_t)HID * HID * 2;
  unsigned short* Qb  = (unsigned short*)p; p += (size_t)NTOK * HID * 2;
  unsigned short* Kb  = (unsigned short*)p; p += (size_t)NTOK * HID * 2;
  unsigned short* VTb = (unsigned short*)p; p += (size_t)NTOK * HID * 2;
  float* ct = (float*)p; p += (size_t)SEQ * 32 * 4;
  float* st = (float*)p; p += (size_t)SEQ * 32 * 4;
  unsigned short* Ab  = xb;   // xb dead after gemm_qkv; reuse for attn output

  const int XN = NTOK * HID / 8, WN = HID * HID / 8;
  const int prep_threads = XN + 4 * WN + SEQ * 32;
  prep<<<dim3((prep_threads + 255) / 256), 256, 0, stream>>>(
      x, qw, kw, vw, ow, xb, wqb, wkb, wvb, wob, ct, st);

  gemm_qkv<<<dim3(NTOK / 128, HID / 128, 3), 256, 0, stream>>>(
      xb, wqb, wkb, wvb, qb, kb, vb, ct, st, Qb, Kb, VTb);

  attn<<<dim3(BATCH * NHEADS, SEQ / 128), 256, 0, stream>>>(Qb, Kb, VTb, Ab);

  gemm_o<<<dim3(NTOK / 128, HID / 64), 256, 0, stream>>>(Ab, wob, ob, out);
}

// Round 13
// 113.898 us; speedup vs baseline: 1.0356x; 1.0087x over previous
//
#include <hip/hip_runtime.h>
#include <hip/hip_bf16.h>

// MultiHeadAttention: x[2,2048,1024] fp32 -> QKV proj + RoPE + softmax attn + O proj
// R13: attn KVBLK=128 (16 tiles -> half the barrier/vmcnt drain points), K dbuf +
// V 3-buf of two 64-key half-tiles (verified 128B-row swizzle), in-register P
// (single pB[8]). GEMMs: 1-D grid + bijective XCD swizzle + tn-fast decode for
// L2 panel reuse.

#define SEQ    2048
#define BATCH  2
#define NHEADS 16
#define HDIM   64
#define HID    1024
#define NTOK   (BATCH*SEQ)   // 4096

typedef __bf16 bf16x8 __attribute__((ext_vector_type(8)));
typedef float  f32x4  __attribute__((ext_vector_type(4)));
typedef float  f32x16 __attribute__((ext_vector_type(16)));
typedef unsigned short u16x8 __attribute__((ext_vector_type(8)));
typedef unsigned int   u32x4 __attribute__((ext_vector_type(4)));

__device__ __forceinline__ unsigned short bfc(float x) {
  return __builtin_bit_cast(unsigned short, (__bf16)x);   // native v_cvt (RNE)
}
__device__ __forceinline__ unsigned int pk(float lo, float hi) {
  return (unsigned int)bfc(lo) | ((unsigned int)bfc(hi) << 16);
}
// swap upper 32 lanes of a with lower 32 lanes of b (gfx950)
__device__ __forceinline__ void plswap(unsigned int& a, unsigned int& b) {
  asm volatile("v_permlane32_swap_b32 %0, %1" : "+v"(a), "+v"(b));
}
#define EXP2(x) __builtin_amdgcn_exp2f(x)
#define MFMA32(a, b, c) __builtin_amdgcn_mfma_f32_32x32x16_bf16(a, b, c, 0, 0, 0)

// async global->LDS, 16B per lane. dest = wave-uniform base (+ lane*16 by HW).
__device__ __forceinline__ void gload16(const void* gptr, void* ldsptr) {
  typedef __attribute__((address_space(3))) unsigned int as3_uint;
  typedef const __attribute__((address_space(1))) unsigned int as1_uint;
  __builtin_amdgcn_global_load_lds(
      (as1_uint*)(unsigned long long)gptr,
      (as3_uint*)(unsigned int)(unsigned long long)ldsptr,
      16, 0, 0);
}

__device__ __forceinline__ void cvt8(const float* __restrict__ s,
                                     unsigned short* __restrict__ d, int i) {
  float4 a = *reinterpret_cast<const float4*>(s + i);
  float4 b = *reinterpret_cast<const float4*>(s + i + 4);
  u16x8 o;
  o[0] = bfc(a.x); o[1] = bfc(a.y); o[2] = bfc(a.z); o[3] = bfc(a.w);
  o[4] = bfc(b.x); o[5] = bfc(b.y); o[6] = bfc(b.z); o[7] = bfc(b.w);
  *reinterpret_cast<u16x8*>(d + i) = o;
}

// ---------------- prep: all converts + rope tables in ONE launch ----------------
__global__ __launch_bounds__(256) void prep(
    const float* __restrict__ x,
    const float* __restrict__ qw, const float* __restrict__ kw,
    const float* __restrict__ vw, const float* __restrict__ ow,
    unsigned short* __restrict__ xb,
    unsigned short* __restrict__ wqb, unsigned short* __restrict__ wkb,
    unsigned short* __restrict__ wvb, unsigned short* __restrict__ wob,
    float* __restrict__ ct, float* __restrict__ st)
{
  const int XN = NTOK * HID / 8;   // 524288
  const int WN = HID * HID / 8;    // 131072 (pow2)
  int tid = blockIdx.x * 256 + threadIdx.x;
  if (tid < XN) {
    cvt8(x, xb, tid * 8);
  } else if (tid < XN + 4 * WN) {
    int r = tid - XN;
    int which = r >> 17;                 // / 131072
    int i = (r & (WN - 1)) * 8;
    const float* s = (which == 0) ? qw : (which == 1) ? kw : (which == 2) ? vw : ow;
    unsigned short* d = (which == 0) ? wqb : (which == 1) ? wkb : (which == 2) ? wvb : wob;
    cvt8(s, d, i);
  } else {
    int idx = tid - (XN + 4 * WN);
    if (idx < SEQ * 32) {
      int p = idx >> 5, j = idx & 31;
      float inv = powf(10000.0f, -(float)(2 * j) * (1.0f / 64.0f));
      float a = (float)p * inv;
      ct[idx] = cosf(a);
      st[idx] = sinf(a);
    }
  }
}

// ---------------- QKV GEMM (3-buf, counted vmcnt, XCD-swizzled 1D grid) ----------------
__global__ __launch_bounds__(256) void gemm_qkv(
    const unsigned short* __restrict__ X,
    const unsigned short* __restrict__ Wq, const unsigned short* __restrict__ Wk,
    const unsigned short* __restrict__ Wv,
    const float* __restrict__ bq, const float* __restrict__ bk, const float* __restrict__ bv,
    const float* __restrict__ ct, const float* __restrict__ st,
    unsigned short* __restrict__ Qo, unsigned short* __restrict__ Ko,
    unsigned short* __restrict__ VTo)   // V^T: [bh][d][s]
{
  __shared__ unsigned short LSH[24576];  // Al[3][4096] @0 | Bl[3][4096] @12288; T reuses first 16384
  // bijective XCD swizzle (768 % 8 == 0), tn-fastest decode for L2 panel reuse
  const int lin = blockIdx.x;
  const int swzb = (lin & 7) * 96 + (lin >> 3);
  const int z = swzb >> 8;               // 0..2
  const int tm = (swzb & 255) >> 3;      // 0..31
  const int tn = swzb & 7;               // 0..7
  const unsigned short* W = (z == 0) ? Wq : (z == 1) ? Wk : Wv;
  const float* bias = (z == 0) ? bq : (z == 1) ? bk : bv;
  const int t = threadIdx.x, w = t >> 6, l = t & 63;
  const int wm = w >> 1, wn = w & 1, g = l >> 4;

  f32x4 acc[4][4] = {};

  const int arow0 = tm * 128, brow0 = tn * 128;
  const int s0 = w * 2, s1 = w * 2 + 1;
  const int r0 = s0 * 16 + (l >> 2), r1 = s1 * 16 + (l >> 2);
  const int kc = (l & 3) * 8;

#define GSTAGE(buf, k0)                                                               \
  {                                                                                   \
    gload16(X + (long)(arow0 + r0) * HID + (k0) + kc, LSH + (buf) * 4096 + s0 * 512); \
    gload16(X + (long)(arow0 + r1) * HID + (k0) + kc, LSH + (buf) * 4096 + s1 * 512); \
    gload16(W + (long)(brow0 + r0) * HID + (k0) + kc, LSH + 12288 + (buf) * 4096 + s0 * 512); \
    gload16(W + (long)(brow0 + r1) * HID + (k0) + kc, LSH + 12288 + (buf) * 4096 + s1 * 512); \
  }

  GSTAGE(0, 0)
  GSTAGE(1, 32)
  asm volatile("s_waitcnt vmcnt(4)" ::: "memory");   // buf0 landed; buf1 in flight
  __builtin_amdgcn_s_barrier();
  int cur = 0, stg = 2;
  for (int k0 = 0; k0 < HID; k0 += 32) {
    if (k0 + 64 < HID) GSTAGE(stg, k0 + 64)
    bf16x8 af[4], bfr[4];
#pragma unroll
    for (int fm = 0; fm < 4; ++fm)
      af[fm] = *reinterpret_cast<const bf16x8*>(
          LSH + cur * 4096 + (wm * 64 + fm * 16 + (l & 15)) * 32 + g * 8);
#pragma unroll
    for (int fn = 0; fn < 4; ++fn)
      bfr[fn] = *reinterpret_cast<const bf16x8*>(
          LSH + 12288 + cur * 4096 + (wn * 64 + fn * 16 + (l & 15)) * 32 + g * 8);
    __builtin_amdgcn_s_setprio(1);
#pragma unroll
    for (int fm = 0; fm < 4; ++fm)
#pragma unroll
      for (int fn = 0; fn < 4; ++fn)
        acc[fm][fn] = __builtin_amdgcn_mfma_f32_16x16x32_bf16(af[fm], bfr[fn], acc[fm][fn], 0, 0, 0);
    __builtin_amdgcn_s_setprio(0);
    if (k0 + 64 < HID) {
      asm volatile("s_waitcnt vmcnt(4)" ::: "memory");   // next buf landed, newest stays in flight
    } else {
      asm volatile("s_waitcnt vmcnt(0)" ::: "memory");
    }
    __builtin_amdgcn_s_barrier();
    cur = (cur == 2) ? 0 : cur + 1;
    stg = (stg == 2) ? 0 : stg + 1;
  }
#undef GSTAGE

  const int colb = brow0 + wn * 64;
  float bsv[4];
#pragma unroll
  for (int fn = 0; fn < 4; ++fn) bsv[fn] = bias[colb + fn * 16 + (l & 15)];

  if (z == 2) {
    // ---- V^T epilogue: C-tile -> LDS transposed (XOR-swizzled) -> coalesced VT store
#pragma unroll
    for (int fm = 0; fm < 4; ++fm) {
      int tok = wm * 64 + fm * 16 + g * 4;
#pragma unroll
      for (int fn = 0; fn < 4; ++fn) {
        int col = wn * 64 + fn * 16 + (l & 15);
        unsigned int u0 = (unsigned int)bfc(acc[fm][fn][0] + bsv[fn]) |
                          ((unsigned int)bfc(acc[fm][fn][1] + bsv[fn]) << 16);
        unsigned int u1 = (unsigned int)bfc(acc[fm][fn][2] + bsv[fn]) |
                          ((unsigned int)bfc(acc[fm][fn][3] + bsv[fn]) << 16);
        uint2 uv; uv.x = u0; uv.y = u1;
        *reinterpret_cast<uint2*>(&LSH[col * 128 + (tok ^ ((col & 7) << 3))]) = uv;
      }
    }
    __syncthreads();
    const int bb = arow0 >> 11, stok = arow0 & (SEQ - 1);
#pragma unroll
    for (int p8 = 0; p8 < 8; ++p8) {
      int col = p8 * 16 + (t >> 4);          // 0..127
      int soff = (t & 15) * 8;
      uint4 v = *reinterpret_cast<const uint4*>(&LSH[col * 128 + (soff ^ ((col & 7) << 3))]);
      int hh = (brow0 + col) >> 6;
      int dd = col & 63;
      unsigned short* dst = VTo + ((long)(bb * NHEADS + hh) * HDIM + dd) * SEQ + stok + soff;
      *reinterpret_cast<uint4*>(dst) = v;
    }
    return;
  }

  // ---- Q/K epilogue: bias + RoPE (+0.125*log2e folded into Q), store [B][H][S][D]
  unsigned short* Out = (z == 0) ? Qo : Ko;
  const int h = colb >> 6;
#pragma unroll
  for (int fm = 0; fm < 4; ++fm) {
#pragma unroll
    for (int r = 0; r < 4; ++r) {
      int grow = arow0 + wm * 64 + fm * 16 + g * 4 + r;
      int b = grow >> 11, sidx = grow & (SEQ - 1);
      unsigned short* ob = Out + ((long)(b * NHEADS + h) * SEQ + sidx) * HDIM;
#pragma unroll
      for (int fn2 = 0; fn2 < 2; ++fn2) {
        int d1 = fn2 * 16 + (l & 15);               // 0..31
        float v1 = acc[fm][fn2][r] + bsv[fn2];
        float v2 = acc[fm][fn2 + 2][r] + bsv[fn2 + 2];
        float c = ct[sidx * 32 + d1], sn = st[sidx * 32 + d1];
        float o1 = v1 * c - v2 * sn;                // d
        float o2 = v2 * c + v1 * sn;                // d+32
        if (z == 0) { o1 *= 0.18033688f; o2 *= 0.18033688f; } // 0.125 * log2(e)
        ob[d1] = bfc(o1);
        ob[d1 + 32] = bfc(o2);
      }
    }
  }
}

// ---------------- flash attention R13: KVBLK=128, 16 tiles ----------------
// 4 waves x 32 q; swapped QK^T on mfma_32x32x16; in-register P (pk+permlane);
// row-sum via ones-A MFMA. K[2] 16KB bufs (128 keys x 64d, 128B rows);
// V[3] 16KB bufs = 2 half-tiles of [64d][64keys] in the verified 128B-row format.
__global__ __launch_bounds__(256, 2) void attn(
    const unsigned short* __restrict__ Qb,
    const unsigned short* __restrict__ Kb,
    const unsigned short* __restrict__ VTb,
    unsigned short* __restrict__ Ob)   // [NTOK][HID] bf16
{
  __shared__ unsigned short Kl[2][128 * 64];   // [key][d], swizzle ^((key&7)<<4)
  __shared__ unsigned short Vl[3][8192];       // [half][d][key64], swizzle ^((d&7)<<4)
  const int bh = blockIdx.x, qt = blockIdx.y;
  const int b = bh >> 4, h = bh & 15;
  const int t = threadIdx.x, w = t >> 6, l = t & 63;
  const long hb = (long)bh * SEQ * HDIM;
  const int hh = l >> 5;          // half-wave index
  const int swz = (l & 7) << 4;   // byte swizzle for row-reads (row&7 == l&7)

  // Q as B-operand: col=l&31 (q), k(d) = dc*16 + hh*8 + j
  const int q0 = qt * 128 + w * 32;
  bf16x8 qf[4];
#pragma unroll
  for (int dc = 0; dc < 4; ++dc)
    qf[dc] = *reinterpret_cast<const bf16x8*>(
        Qb + hb + (long)(q0 + (l & 31)) * HDIM + dc * 16 + hh * 8);

  f32x16 oacc[2] = {};           // O^T d-blocks; col=q=l&31
  f32x16 oaccE = {};             // every reg = row-sum of P for q=l&31
  const f32x16 FZ16 = {};

  // ones A-fragment (bf16 1.0 x8)
  u32x4 ou; ou[0] = 0x3F803F80u; ou[1] = 0x3F803F80u; ou[2] = 0x3F803F80u; ou[3] = 0x3F803F80u;
  const bf16x8 ones8 = __builtin_bit_cast(bf16x8, ou);

  // staging pointers (advance by one 128-key tile per STAGE)
  const int srow = l >> 3;
  const int scol = (((l & 7) * 16) ^ ((l >> 3) << 4)) >> 1;
  const unsigned short* kp0 = Kb + hb + (long)(w * 32 + srow) * HDIM + scol;
  const unsigned short* kp1 = kp0 + 8 * HDIM;
  const unsigned short* kp2 = kp0 + 16 * HDIM;
  const unsigned short* kp3 = kp0 + 24 * HDIM;
  const unsigned short* vp0 = VTb + hb + (long)(w * 16 + srow) * SEQ + scol;   // half0 rows w16..+7
  const unsigned short* vp1 = vp0 + 8 * SEQ;                                   // half0 rows +8
  const unsigned short* vp2 = vp0 + 64;                                        // half1
  const unsigned short* vp3 = vp1 + 64;

#define STAGE(kbuf, vbuf)                                                   \
  {                                                                         \
    gload16(kp0, (char*)Kl + (kbuf) * 16384 + w * 4096);                    \
    gload16(kp1, (char*)Kl + (kbuf) * 16384 + w * 4096 + 1024);             \
    gload16(kp2, (char*)Kl + (kbuf) * 16384 + w * 4096 + 2048);             \
    gload16(kp3, (char*)Kl + (kbuf) * 16384 + w * 4096 + 3072);             \
    gload16(vp0, (char*)Vl + (vbuf) * 16384 + w * 2048);                    \
    gload16(vp1, (char*)Vl + (vbuf) * 16384 + w * 2048 + 1024);             \
    gload16(vp2, (char*)Vl + (vbuf) * 16384 + 8192 + w * 2048);             \
    gload16(vp3, (char*)Vl + (vbuf) * 16384 + 8192 + w * 2048 + 1024);      \
    kp0 += 128 * HDIM; kp1 += 128 * HDIM; kp2 += 128 * HDIM; kp3 += 128 * HDIM; \
    vp0 += 128; vp1 += 128; vp2 += 128; vp3 += 128;                         \
  }

// S^T = K Q : sa[blk] covers keys 32blk..32blk+31 for this wave's 32 q
#define QK(kbuf)                                                                  \
  _Pragma("unroll")                                                               \
  for (int blk = 0; blk < 4; ++blk) {                                             \
    const char* kb_ = (char*)Kl + (kbuf) * 16384 + (32 * blk + (l & 31)) * 128;   \
    bf16x8 kf0 = *reinterpret_cast<const bf16x8*>(kb_ + ((0 * 32 + hh * 16) ^ swz)); \
    sa[blk] = MFMA32(kf0, qf[0], FZ16);                                           \
    bf16x8 kf1 = *reinterpret_cast<const bf16x8*>(kb_ + ((1 * 32 + hh * 16) ^ swz)); \
    sa[blk] = MFMA32(kf1, qf[1], sa[blk]);                                        \
    bf16x8 kf2 = *reinterpret_cast<const bf16x8*>(kb_ + ((2 * 32 + hh * 16) ^ swz)); \
    sa[blk] = MFMA32(kf2, qf[2], sa[blk]);                                        \
    bf16x8 kf3 = *reinterpret_cast<const bf16x8*>(kb_ + ((3 * 32 + hh * 16) ^ swz)); \
    sa[blk] = MFMA32(kf3, qf[3], sa[blk]);                                        \
  }

#define SOFTEXP                                                                   \
  _Pragma("unroll")                                                               \
  for (int blk = 0; blk < 4; ++blk)                                               \
    _Pragma("unroll")                                                             \
    for (int r = 0; r < 16; ++r) sa[blk][r] = EXP2(sa[blk][r]);

// build PV B-frags in-register: pB[2blk+c] = keys 16(2blk+c)+8h+{0..7} for q=l&31
#define PBUILD                                                                    \
  _Pragma("unroll")                                                               \
  for (int blk = 0; blk < 4; ++blk) {                                             \
    unsigned int w0a = pk(sa[blk][0], sa[blk][1]);                                \
    unsigned int w1a = pk(sa[blk][2], sa[blk][3]);                                \
    unsigned int w0b = pk(sa[blk][4], sa[blk][5]);                                \
    unsigned int w1b = pk(sa[blk][6], sa[blk][7]);                                \
    unsigned int w0c = pk(sa[blk][8], sa[blk][9]);                                \
    unsigned int w1c = pk(sa[blk][10], sa[blk][11]);                              \
    unsigned int w0d = pk(sa[blk][12], sa[blk][13]);                              \
    unsigned int w1d = pk(sa[blk][14], sa[blk][15]);                              \
    plswap(w0a, w0b); plswap(w1a, w1b);                                           \
    plswap(w0c, w0d); plswap(w1c, w1d);                                           \
    u32x4 f0; f0[0] = w0a; f0[1] = w1a; f0[2] = w0b; f0[3] = w1b;                 \
    u32x4 f1; f1[0] = w0c; f1[1] = w1c; f1[2] = w0d; f1[3] = w1d;                 \
    pB[2 * blk + 0] = __builtin_bit_cast(bf16x8, f0);                             \
    pB[2 * blk + 1] = __builtin_bit_cast(bf16x8, f1);                             \
  }

// O^T += V^T P ; oaccE += 1*P (row-sum). kc 0..7 over 128 keys; half = kc>>2.
#define PVSTEP(vbuf)                                                              \
  _Pragma("unroll")                                                               \
  for (int db = 0; db < 2; ++db) {                                                \
    _Pragma("unroll")                                                             \
    for (int kc = 0; kc < 8; ++kc) {                                              \
      const char* vb_ = (char*)Vl + (vbuf) * 16384 + (kc >> 2) * 8192 +           \
                        (32 * db + (l & 31)) * 128 + (((kc & 3) * 32 + hh * 16) ^ swz); \
      bf16x8 vf = *reinterpret_cast<const bf16x8*>(vb_);                          \
      oacc[db] = MFMA32(vf, pB[kc], oacc[db]);                                    \
    }                                                                             \
  }                                                                               \
  _Pragma("unroll")                                                               \
  for (int kc = 0; kc < 8; ++kc) oaccE = MFMA32(ones8, pB[kc], oaccE);

#define ITER(KB, VR, VW)                                   \
  {                                                        \
    STAGE(KB ^ 1, VW)                                      \
    __builtin_amdgcn_s_setprio(1);                         \
    QK(KB)                                                 \
    PVSTEP(VR)                                             \
    __builtin_amdgcn_s_setprio(0);                         \
    SOFTEXP                                                \
    PBUILD                                                 \
    asm volatile("s_waitcnt vmcnt(0)" ::: "memory");       \
    __builtin_amdgcn_s_barrier();                          \
  }
#define ITER_NOSTAGE(KB, VR)                               \
  {                                                        \
    __builtin_amdgcn_s_setprio(1);                         \
    QK(KB)                                                 \
    PVSTEP(VR)                                             \
    __builtin_amdgcn_s_setprio(0);                         \
    SOFTEXP                                                \
    PBUILD                                                 \
    asm volatile("s_waitcnt vmcnt(0)" ::: "memory");       \
    __builtin_amdgcn_s_barrier();                          \
  }

  f32x16 sa[4];
  bf16x8 pB[8];

  // prologue: stage tile 0 into K[0],V[0]
  STAGE(0, 0)
  asm volatile("s_waitcnt vmcnt(0)" ::: "memory");
  __builtin_amdgcn_s_barrier();

  // peeled t=0: stage tile 1 -> K[1],V[1]; QK(0); exp2+PBUILD; no PV yet
  STAGE(1, 1)
  __builtin_amdgcn_s_setprio(1);
  QK(0)
  __builtin_amdgcn_s_setprio(0);
  SOFTEXP
  PBUILD
  asm volatile("s_waitcnt vmcnt(0)" ::: "memory");
  __builtin_amdgcn_s_barrier();

  // main: t=1..14 with (KB=t&1, VR=(t-1)%3, VW=(t+1)%3); period 6
  for (int m = 0; m < 2; ++m) {
    ITER(1, 0, 2)
    ITER(0, 1, 0)
    ITER(1, 2, 1)
    ITER(0, 0, 2)
    ITER(1, 1, 0)
    ITER(0, 2, 1)
  }
  ITER(1, 0, 2)        // t=13
  ITER(0, 1, 0)        // t=14 (stages tile 15 -> V[0])
  ITER_NOSTAGE(1, 2)   // t=15 (QK(15), PV(14))

  // epilogue: PV of tile 15 (P in pB, V in Vl[0])
  __builtin_amdgcn_s_setprio(1);
  PVSTEP(0)
  __builtin_amdgcn_s_setprio(0);

#undef STAGE
#undef QK
#undef SOFTEXP
#undef PBUILD
#undef PVSTEP
#undef ITER
#undef ITER_NOSTAGE

  // ---- normalize + store O^T (lane owns q = q0+(l&31); d = (r&3)+8(r>>2)+4hh+32db)
  {
    float inv = 1.0f / oaccE[0];
    int q = q0 + (l & 31);
    unsigned short* op = Ob + (long)(b * SEQ + q) * HID + h * HDIM;
#pragma unroll
    for (int db = 0; db < 2; ++db)
#pragma unroll
      for (int a = 0; a < 4; ++a) {
        int d = 8 * a + 4 * hh + 32 * db;
        unsigned int lo = pk(oacc[db][4 * a + 0] * inv, oacc[db][4 * a + 1] * inv);
        unsigned int hi2 = pk(oacc[db][4 * a + 2] * inv, oacc[db][4 * a + 3] * inv);
        uint2 uv; uv.x = lo; uv.y = hi2;
        *reinterpret_cast<uint2*>(op + d) = uv;
      }
  }
}

// ---------------- output projection (3-buf counted vmcnt, 128x64 tile, XCD swizzle) ----------------
__global__ __launch_bounds__(256) void gemm_o(
    const unsigned short* __restrict__ A,
    const unsigned short* __restrict__ W,
    const float* __restrict__ bias,
    float* __restrict__ Out)
{
  __shared__ unsigned short Al[3][128 * 32];
  __shared__ unsigned short Bl[3][64 * 32];
  // bijective XCD swizzle (512 % 8 == 0), tn-fastest decode
  const int lin = blockIdx.x;
  const int swzb = (lin & 7) * 64 + (lin >> 3);
  const int tm = swzb >> 4, tn = swzb & 15;
  const int t = threadIdx.x, w = t >> 6, l = t & 63;
  const int wm = w >> 1, wn = w & 1;

  f32x4 acc[4][2] = {};
  const int arow0 = tm * 128, brow0 = tn * 64;
  const int s0 = w * 2, s1 = w * 2 + 1;
  const int r0 = s0 * 16 + (l >> 2), r1 = s1 * 16 + (l >> 2);
  const int rb = w * 16 + (l >> 2);
  const int kc = (l & 3) * 8;

#define GSTAGE(buf, k0)                                                       \
  {                                                                           \
    gload16(A + (long)(arow0 + r0) * HID + (k0) + kc, Al[buf] + s0 * 512);    \
    gload16(A + (long)(arow0 + r1) * HID + (k0) + kc, Al[buf] + s1 * 512);    \
    gload16(W + (long)(brow0 + rb) * HID + (k0) + kc, Bl[buf] + w * 512);     \
  }

  GSTAGE(0, 0)
  GSTAGE(1, 32)
  asm volatile("s_waitcnt vmcnt(3)" ::: "memory");
  __builtin_amdgcn_s_barrier();
  int cur = 0, stg = 2;
  for (int k0 = 0; k0 < HID; k0 += 32) {
    if (k0 + 64 < HID) GSTAGE(stg, k0 + 64)
    bf16x8 af[4], bfr[2];
#pragma unroll
    for (int fm = 0; fm < 4; ++fm)
      af[fm] = *reinterpret_cast<const bf16x8*>(Al[cur] + (wm * 64 + fm * 16 + (l & 15)) * 32 + (l >> 4) * 8);
#pragma unroll
    for (int fn = 0; fn < 2; ++fn)
      bfr[fn] = *reinterpret_cast<const bf16x8*>(Bl[cur] + (wn * 32 + fn * 16 + (l & 15)) * 32 + (l >> 4) * 8);
    __builtin_amdgcn_s_setprio(1);
#pragma unroll
    for (int fm = 0; fm < 4; ++fm)
#pragma unroll
      for (int fn = 0; fn < 2; ++fn)
        acc[fm][fn] = __builtin_amdgcn_mfma_f32_16x16x32_bf16(af[fm], bfr[fn], acc[fm][fn], 0, 0, 0);
    __builtin_amdgcn_s_setprio(0);
    if (k0 + 64 < HID) {
      asm volatile("s_waitcnt vmcnt(3)" ::: "memory");
    } else {
      asm volatile("s_waitcnt vmcnt(0)" ::: "memory");
    }
    __builtin_amdgcn_s_barrier();
    cur = (cur == 2) ? 0 : cur + 1;
    stg = (stg == 2) ? 0 : stg + 1;
  }
#undef GSTAGE

  const int colb = brow0 + wn * 32;
  float bsv[2];
#pragma unroll
  for (int fn = 0; fn < 2; ++fn) bsv[fn] = bias[colb + fn * 16 + (l & 15)];
#pragma unroll
  for (int fm = 0; fm < 4; ++fm)
#pragma unroll
    for (int r = 0; r < 4; ++r) {
      int grow = arow0 + wm * 64 + fm * 16 + (l >> 4) * 4 + r;
#pragma unroll
      for (int fn = 0; fn < 2; ++fn)
        Out[(long)grow * HID + colb + fn * 16 + (l & 15)] = acc[fm][fn][r] + bsv[fn];
    }
}

extern "C" void kernel_launch(void* const* d_in, const int* in_sizes, int n_in,
                              void* d_out, int out_size, void* d_ws, size_t ws_size,
                              hipStream_t stream) {
  const float* x  = (const float*)d_in[0];
  const float* qw = (const float*)d_in[1];
  const float* qb = (const float*)d_in[2];
  const float* kw = (const float*)d_in[3];
  const float* kb = (const float*)d_in[4];
  const float* vw = (const float*)d_in[5];
  const float* vb = (const float*)d_in[6];
  const float* ow = (const float*)d_in[7];
  const float* ob = (const float*)d_in[8];
  float* out = (float*)d_out;

  char* p = (char*)d_ws;
  unsigned short* xb  = (unsigned short*)p; p += (size_t)NTOK * HID * 2;
  unsigned short* wqb = (unsigned short*)p; p += (size_t)HID * HID * 2;
  unsigned short* wkb = (unsigned short*)p; p += (size_t)HID * HID * 2;
  unsigned short* wvb = (unsigned short*)p; p += (size_t)HID * HID * 2;
  unsigned short* wob = (unsigned short*)p; p += (size_t)HID * HID * 2;
  unsigned short* Qb  = (unsigned short*)p; p += (size_t)NTOK * HID * 2;
  unsigned short* Kb  = (unsigned short*)p; p += (size_t)NTOK * HID * 2;
  unsigned short* VTb = (unsigned short*)p; p += (size_t)NTOK * HID * 2;
  float* ct = (float*)p; p += (size_t)SEQ * 32 * 4;
  float* st = (float*)p; p += (size_t)SEQ * 32 * 4;
  unsigned short* Ab  = xb;   // xb dead after gemm_qkv; reuse for attn output

  const int XN = NTOK * HID / 8, WN = HID * HID / 8;
  const int prep_threads = XN + 4 * WN + SEQ * 32;
  prep<<<dim3((prep_threads + 255) / 256), 256, 0, stream>>>(
      x, qw, kw, vw, ow, xb, wqb, wkb, wvb, wob, ct, st);

  gemm_qkv<<<dim3(768), 256, 0, stream>>>(
      xb, wqb, wkb, wvb, qb, kb, vb, ct, st, Qb, Kb, VTb);

  attn<<<dim3(BATCH * NHEADS, SEQ / 128), 256, 0, stream>>>(Qb, Kb, VTb, Ab);

  gemm_o<<<dim3(512), 256, 0, stream>>>(Ab, wob, ob, out);
}

// Round 14
// 113.690 us; speedup vs baseline: 1.0375x; 1.0018x over previous
//
#include <hip/hip_runtime.h>
#include <hip/hip_bf16.h>

// MultiHeadAttention: x[2,2048,1024] fp32 -> QKV proj + RoPE + softmax attn + O proj
// R14: attn depth-2 prefetch: K[4]/V[4] ring (KVBLK=64), stage tile t+2 during
// iter t, counted vmcnt(4) at tile boundaries (never drain mid-loop). In-register
// P (pk+permlane), ones-A MFMA row-sum. GEMM grids reverted to 2-D (R10 form).

#define SEQ    2048
#define BATCH  2
#define NHEADS 16
#define HDIM   64
#define HID    1024
#define NTOK   (BATCH*SEQ)   // 4096

typedef __bf16 bf16x8 __attribute__((ext_vector_type(8)));
typedef float  f32x4  __attribute__((ext_vector_type(4)));
typedef float  f32x16 __attribute__((ext_vector_type(16)));
typedef unsigned short u16x8 __attribute__((ext_vector_type(8)));
typedef unsigned int   u32x4 __attribute__((ext_vector_type(4)));

__device__ __forceinline__ unsigned short bfc(float x) {
  return __builtin_bit_cast(unsigned short, (__bf16)x);   // native v_cvt (RNE)
}
__device__ __forceinline__ unsigned int pk(float lo, float hi) {
  return (unsigned int)bfc(lo) | ((unsigned int)bfc(hi) << 16);
}
// swap upper 32 lanes of a with lower 32 lanes of b (gfx950)
__device__ __forceinline__ void plswap(unsigned int& a, unsigned int& b) {
  asm volatile("v_permlane32_swap_b32 %0, %1" : "+v"(a), "+v"(b));
}
#define EXP2(x) __builtin_amdgcn_exp2f(x)
#define MFMA32(a, b, c) __builtin_amdgcn_mfma_f32_32x32x16_bf16(a, b, c, 0, 0, 0)

// async global->LDS, 16B per lane. dest = wave-uniform base (+ lane*16 by HW).
__device__ __forceinline__ void gload16(const void* gptr, void* ldsptr) {
  typedef __attribute__((address_space(3))) unsigned int as3_uint;
  typedef const __attribute__((address_space(1))) unsigned int as1_uint;
  __builtin_amdgcn_global_load_lds(
      (as1_uint*)(unsigned long long)gptr,
      (as3_uint*)(unsigned int)(unsigned long long)ldsptr,
      16, 0, 0);
}

__device__ __forceinline__ void cvt8(const float* __restrict__ s,
                                     unsigned short* __restrict__ d, int i) {
  float4 a = *reinterpret_cast<const float4*>(s + i);
  float4 b = *reinterpret_cast<const float4*>(s + i + 4);
  u16x8 o;
  o[0] = bfc(a.x); o[1] = bfc(a.y); o[2] = bfc(a.z); o[3] = bfc(a.w);
  o[4] = bfc(b.x); o[5] = bfc(b.y); o[6] = bfc(b.z); o[7] = bfc(b.w);
  *reinterpret_cast<u16x8*>(d + i) = o;
}

// ---------------- prep: all converts + rope tables in ONE launch ----------------
__global__ __launch_bounds__(256) void prep(
    const float* __restrict__ x,
    const float* __restrict__ qw, const float* __restrict__ kw,
    const float* __restrict__ vw, const float* __restrict__ ow,
    unsigned short* __restrict__ xb,
    unsigned short* __restrict__ wqb, unsigned short* __restrict__ wkb,
    unsigned short* __restrict__ wvb, unsigned short* __restrict__ wob,
    float* __restrict__ ct, float* __restrict__ st)
{
  const int XN = NTOK * HID / 8;   // 524288
  const int WN = HID * HID / 8;    // 131072 (pow2)
  int tid = blockIdx.x * 256 + threadIdx.x;
  if (tid < XN) {
    cvt8(x, xb, tid * 8);
  } else if (tid < XN + 4 * WN) {
    int r = tid - XN;
    int which = r >> 17;                 // / 131072
    int i = (r & (WN - 1)) * 8;
    const float* s = (which == 0) ? qw : (which == 1) ? kw : (which == 2) ? vw : ow;
    unsigned short* d = (which == 0) ? wqb : (which == 1) ? wkb : (which == 2) ? wvb : wob;
    cvt8(s, d, i);
  } else {
    int idx = tid - (XN + 4 * WN);
    if (idx < SEQ * 32) {
      int p = idx >> 5, j = idx & 31;
      float inv = powf(10000.0f, -(float)(2 * j) * (1.0f / 64.0f));
      float a = (float)p * inv;
      ct[idx] = cosf(a);
      st[idx] = sinf(a);
    }
  }
}

// ---------------- QKV GEMM (3-buf, counted vmcnt) + bias/RoPE epilogue; z==2 -> V^T ----------------
__global__ __launch_bounds__(256) void gemm_qkv(
    const unsigned short* __restrict__ X,
    const unsigned short* __restrict__ Wq, const unsigned short* __restrict__ Wk,
    const unsigned short* __restrict__ Wv,
    const float* __restrict__ bq, const float* __restrict__ bk, const float* __restrict__ bv,
    const float* __restrict__ ct, const float* __restrict__ st,
    unsigned short* __restrict__ Qo, unsigned short* __restrict__ Ko,
    unsigned short* __restrict__ VTo)   // V^T: [bh][d][s]
{
  __shared__ unsigned short LSH[24576];  // Al[3][4096] @0 | Bl[3][4096] @12288; T reuses first 16384
  const int z = blockIdx.z;
  const unsigned short* W = (z == 0) ? Wq : (z == 1) ? Wk : Wv;
  const float* bias = (z == 0) ? bq : (z == 1) ? bk : bv;
  const int tm = blockIdx.x, tn = blockIdx.y;
  const int t = threadIdx.x, w = t >> 6, l = t & 63;
  const int wm = w >> 1, wn = w & 1, g = l >> 4;

  f32x4 acc[4][4] = {};

  const int arow0 = tm * 128, brow0 = tn * 128;
  const int s0 = w * 2, s1 = w * 2 + 1;
  const int r0 = s0 * 16 + (l >> 2), r1 = s1 * 16 + (l >> 2);
  const int kc = (l & 3) * 8;

#define GSTAGE(buf, k0)                                                               \
  {                                                                                   \
    gload16(X + (long)(arow0 + r0) * HID + (k0) + kc, LSH + (buf) * 4096 + s0 * 512); \
    gload16(X + (long)(arow0 + r1) * HID + (k0) + kc, LSH + (buf) * 4096 + s1 * 512); \
    gload16(W + (long)(brow0 + r0) * HID + (k0) + kc, LSH + 12288 + (buf) * 4096 + s0 * 512); \
    gload16(W + (long)(brow0 + r1) * HID + (k0) + kc, LSH + 12288 + (buf) * 4096 + s1 * 512); \
  }

  GSTAGE(0, 0)
  GSTAGE(1, 32)
  asm volatile("s_waitcnt vmcnt(4)" ::: "memory");   // buf0 landed; buf1 in flight
  __builtin_amdgcn_s_barrier();
  int cur = 0, stg = 2;
  for (int k0 = 0; k0 < HID; k0 += 32) {
    if (k0 + 64 < HID) GSTAGE(stg, k0 + 64)
    bf16x8 af[4], bfr[4];
#pragma unroll
    for (int fm = 0; fm < 4; ++fm)
      af[fm] = *reinterpret_cast<const bf16x8*>(
          LSH + cur * 4096 + (wm * 64 + fm * 16 + (l & 15)) * 32 + g * 8);
#pragma unroll
    for (int fn = 0; fn < 4; ++fn)
      bfr[fn] = *reinterpret_cast<const bf16x8*>(
          LSH + 12288 + cur * 4096 + (wn * 64 + fn * 16 + (l & 15)) * 32 + g * 8);
    __builtin_amdgcn_s_setprio(1);
#pragma unroll
    for (int fm = 0; fm < 4; ++fm)
#pragma unroll
      for (int fn = 0; fn < 4; ++fn)
        acc[fm][fn] = __builtin_amdgcn_mfma_f32_16x16x32_bf16(af[fm], bfr[fn], acc[fm][fn], 0, 0, 0);
    __builtin_amdgcn_s_setprio(0);
    if (k0 + 64 < HID) {
      asm volatile("s_waitcnt vmcnt(4)" ::: "memory");   // next buf landed, newest stays in flight
    } else {
      asm volatile("s_waitcnt vmcnt(0)" ::: "memory");
    }
    __builtin_amdgcn_s_barrier();
    cur = (cur == 2) ? 0 : cur + 1;
    stg = (stg == 2) ? 0 : stg + 1;
  }
#undef GSTAGE

  const int colb = brow0 + wn * 64;
  float bsv[4];
#pragma unroll
  for (int fn = 0; fn < 4; ++fn) bsv[fn] = bias[colb + fn * 16 + (l & 15)];

  if (z == 2) {
    // ---- V^T epilogue: C-tile -> LDS transposed (XOR-swizzled) -> coalesced VT store
#pragma unroll
    for (int fm = 0; fm < 4; ++fm) {
      int tok = wm * 64 + fm * 16 + g * 4;
#pragma unroll
      for (int fn = 0; fn < 4; ++fn) {
        int col = wn * 64 + fn * 16 + (l & 15);
        unsigned int u0 = (unsigned int)bfc(acc[fm][fn][0] + bsv[fn]) |
                          ((unsigned int)bfc(acc[fm][fn][1] + bsv[fn]) << 16);
        unsigned int u1 = (unsigned int)bfc(acc[fm][fn][2] + bsv[fn]) |
                          ((unsigned int)bfc(acc[fm][fn][3] + bsv[fn]) << 16);
        uint2 uv; uv.x = u0; uv.y = u1;
        *reinterpret_cast<uint2*>(&LSH[col * 128 + (tok ^ ((col & 7) << 3))]) = uv;
      }
    }
    __syncthreads();
    const int bb = arow0 >> 11, stok = arow0 & (SEQ - 1);
#pragma unroll
    for (int p8 = 0; p8 < 8; ++p8) {
      int col = p8 * 16 + (t >> 4);          // 0..127
      int soff = (t & 15) * 8;
      uint4 v = *reinterpret_cast<const uint4*>(&LSH[col * 128 + (soff ^ ((col & 7) << 3))]);
      int hh = (brow0 + col) >> 6;
      int dd = col & 63;
      unsigned short* dst = VTo + ((long)(bb * NHEADS + hh) * HDIM + dd) * SEQ + stok + soff;
      *reinterpret_cast<uint4*>(dst) = v;
    }
    return;
  }

  // ---- Q/K epilogue: bias + RoPE (+0.125*log2e folded into Q), store [B][H][S][D]
  unsigned short* Out = (z == 0) ? Qo : Ko;
  const int h = colb >> 6;
#pragma unroll
  for (int fm = 0; fm < 4; ++fm) {
#pragma unroll
    for (int r = 0; r < 4; ++r) {
      int grow = arow0 + wm * 64 + fm * 16 + g * 4 + r;
      int b = grow >> 11, sidx = grow & (SEQ - 1);
      unsigned short* ob = Out + ((long)(b * NHEADS + h) * SEQ + sidx) * HDIM;
#pragma unroll
      for (int fn2 = 0; fn2 < 2; ++fn2) {
        int d1 = fn2 * 16 + (l & 15);               // 0..31
        float v1 = acc[fm][fn2][r] + bsv[fn2];
        float v2 = acc[fm][fn2 + 2][r] + bsv[fn2 + 2];
        float c = ct[sidx * 32 + d1], sn = st[sidx * 32 + d1];
        float o1 = v1 * c - v2 * sn;                // d
        float o2 = v2 * c + v1 * sn;                // d+32
        if (z == 0) { o1 *= 0.18033688f; o2 *= 0.18033688f; } // 0.125 * log2(e)
        ob[d1] = bfc(o1);
        ob[d1 + 32] = bfc(o2);
      }
    }
  }
}

// ---------------- flash attention R14: depth-2 prefetch, K[4]/V[4] ring ----------------
// 4 waves x 32 q; KVBLK=64, 32 tiles. At iter t: QK reads K[t&3], PV reads
// V[(t-1)&3], stage writes buf (t+2)&3; end-of-iter vmcnt(4) (t+1 complete,
// t+2 in flight). In-register P; ones-A MFMA row-sum. LDS 64KB, 2 blocks/CU.
__global__ __launch_bounds__(256, 2) void attn(
    const unsigned short* __restrict__ Qb,
    const unsigned short* __restrict__ Kb,
    const unsigned short* __restrict__ VTb,
    unsigned short* __restrict__ Ob)   // [NTOK][HID] bf16
{
  __shared__ unsigned short Kl[4][64 * 64];    // [key][d], swizzle ^((key&7)<<4)
  __shared__ unsigned short Vl[4][64 * 64];    // [d][key], swizzle ^((d&7)<<4)
  const int bh = blockIdx.x, qt = blockIdx.y;
  const int b = bh >> 4, h = bh & 15;
  const int t = threadIdx.x, w = t >> 6, l = t & 63;
  const long hb = (long)bh * SEQ * HDIM;
  const int hh = l >> 5;          // half-wave index
  const int swz = (l & 7) << 4;   // byte swizzle for row-reads (row&7 == l&7)

  // Q as B-operand: col=l&31 (q), k(d) = dc*16 + hh*8 + j
  const int q0 = qt * 128 + w * 32;
  bf16x8 qf[4];
#pragma unroll
  for (int dc = 0; dc < 4; ++dc)
    qf[dc] = *reinterpret_cast<const bf16x8*>(
        Qb + hb + (long)(q0 + (l & 31)) * HDIM + dc * 16 + hh * 8);

  f32x16 oacc[2] = {};           // O^T d-blocks; col=q=l&31
  f32x16 oaccE = {};             // every reg = row-sum of P for q=l&31
  const f32x16 FZ16 = {};

  // ones A-fragment (bf16 1.0 x8)
  u32x4 ou; ou[0] = 0x3F803F80u; ou[1] = 0x3F803F80u; ou[2] = 0x3F803F80u; ou[3] = 0x3F803F80u;
  const bf16x8 ones8 = __builtin_bit_cast(bf16x8, ou);

  // staging pointers (advance by one 64-key tile per STAGE)
  const int srow = l >> 3;
  const int scol = (((l & 7) * 16) ^ ((l >> 3) << 4)) >> 1;
  const unsigned short* kp0 = Kb + hb + (long)(w * 16 + srow) * HDIM + scol;
  const unsigned short* kp1 = kp0 + 8 * HDIM;
  const unsigned short* vp0 = VTb + hb + (long)(w * 16 + srow) * SEQ + scol;
  const unsigned short* vp1 = vp0 + 8 * SEQ;

#define STAGE(buf)                                                     \
  {                                                                    \
    gload16(kp0, (char*)Kl + (buf) * 8192 + w * 2048);                 \
    gload16(kp1, (char*)Kl + (buf) * 8192 + w * 2048 + 1024);          \
    gload16(vp0, (char*)Vl + (buf) * 8192 + w * 2048);                 \
    gload16(vp1, (char*)Vl + (buf) * 8192 + w * 2048 + 1024);          \
    kp0 += 64 * HDIM; kp1 += 64 * HDIM; vp0 += 64; vp1 += 64;          \
  }

// S^T = K Q : sa[blk] covers keys 32blk..32blk+31 for this wave's 32 q
#define QK(kbuf)                                                                  \
  _Pragma("unroll")                                                               \
  for (int blk = 0; blk < 2; ++blk) {                                             \
    const char* kb_ = (char*)Kl + (kbuf) * 8192 + (32 * blk + (l & 31)) * 128;    \
    bf16x8 kf0 = *reinterpret_cast<const bf16x8*>(kb_ + ((0 * 32 + hh * 16) ^ swz)); \
    sa[blk] = MFMA32(kf0, qf[0], FZ16);                                           \
    bf16x8 kf1 = *reinterpret_cast<const bf16x8*>(kb_ + ((1 * 32 + hh * 16) ^ swz)); \
    sa[blk] = MFMA32(kf1, qf[1], sa[blk]);                                        \
    bf16x8 kf2 = *reinterpret_cast<const bf16x8*>(kb_ + ((2 * 32 + hh * 16) ^ swz)); \
    sa[blk] = MFMA32(kf2, qf[2], sa[blk]);                                        \
    bf16x8 kf3 = *reinterpret_cast<const bf16x8*>(kb_ + ((3 * 32 + hh * 16) ^ swz)); \
    sa[blk] = MFMA32(kf3, qf[3], sa[blk]);                                        \
  }

#define SOFTEXP                                                                   \
  _Pragma("unroll")                                                               \
  for (int blk = 0; blk < 2; ++blk)                                               \
    _Pragma("unroll")                                                             \
    for (int r = 0; r < 16; ++r) sa[blk][r] = EXP2(sa[blk][r]);

// build PV B-frags in-register: pB[2blk+c] = keys 16(2blk+c)+8h+{0..7} for q=l&31
#define PBUILD                                                                    \
  _Pragma("unroll")                                                               \
  for (int blk = 0; blk < 2; ++blk) {                                             \
    unsigned int w0a = pk(sa[blk][0], sa[blk][1]);                                \
    unsigned int w1a = pk(sa[blk][2], sa[blk][3]);                                \
    unsigned int w0b = pk(sa[blk][4], sa[blk][5]);                                \
    unsigned int w1b = pk(sa[blk][6], sa[blk][7]);                                \
    unsigned int w0c = pk(sa[blk][8], sa[blk][9]);                                \
    unsigned int w1c = pk(sa[blk][10], sa[blk][11]);                              \
    unsigned int w0d = pk(sa[blk][12], sa[blk][13]);                              \
    unsigned int w1d = pk(sa[blk][14], sa[blk][15]);                              \
    plswap(w0a, w0b); plswap(w1a, w1b);                                           \
    plswap(w0c, w0d); plswap(w1c, w1d);                                           \
    u32x4 f0; f0[0] = w0a; f0[1] = w1a; f0[2] = w0b; f0[3] = w1b;                 \
    u32x4 f1; f1[0] = w0c; f1[1] = w1c; f1[2] = w0d; f1[3] = w1d;                 \
    pB[2 * blk + 0] = __builtin_bit_cast(bf16x8, f0);                             \
    pB[2 * blk + 1] = __builtin_bit_cast(bf16x8, f1);                             \
  }

// O^T += V^T P ; oaccE += 1*P (row-sum)
#define PVSTEP(vbuf)                                                              \
  _Pragma("unroll")                                                               \
  for (int db = 0; db < 2; ++db) {                                                \
    const char* vb_ = (char*)Vl + (vbuf) * 8192 + (32 * db + (l & 31)) * 128;     \
    _Pragma("unroll")                                                             \
    for (int kc = 0; kc < 4; ++kc) {                                              \
      bf16x8 vf = *reinterpret_cast<const bf16x8*>(vb_ + ((kc * 32 + hh * 16) ^ swz)); \
      oacc[db] = MFMA32(vf, pB[kc], oacc[db]);                                    \
    }                                                                             \
  }                                                                               \
  _Pragma("unroll")                                                               \
  for (int kc = 0; kc < 4; ++kc) oaccE = MFMA32(ones8, pB[kc], oaccE);

#define ITER(KB, VR, SW)                                   \
  {                                                        \
    STAGE(SW)                                              \
    __builtin_amdgcn_s_setprio(1);                         \
    QK(KB)                                                 \
    PVSTEP(VR)                                             \
    __builtin_amdgcn_s_setprio(0);                         \
    SOFTEXP                                                \
    PBUILD                                                 \
    asm volatile("s_waitcnt vmcnt(4)" ::: "memory");       \
    __builtin_amdgcn_s_barrier();                          \
  }
#define ITER_DRAIN(KB, VR)                                 \
  {                                                        \
    __builtin_amdgcn_s_setprio(1);                         \
    QK(KB)                                                 \
    PVSTEP(VR)                                             \
    __builtin_amdgcn_s_setprio(0);                         \
    SOFTEXP                                                \
    PBUILD                                                 \
    asm volatile("s_waitcnt vmcnt(0)" ::: "memory");       \
    __builtin_amdgcn_s_barrier();                          \
  }
#define ITER_LAST(KB, VR)                                  \
  {                                                        \
    __builtin_amdgcn_s_setprio(1);                         \
    QK(KB)                                                 \
    PVSTEP(VR)                                             \
    __builtin_amdgcn_s_setprio(0);                         \
    SOFTEXP                                                \
    PBUILD                                                 \
  }

  f32x16 sa[2];
  bf16x8 pB[4];

  // prologue: stage tiles 0,1
  STAGE(0)
  STAGE(1)
  asm volatile("s_waitcnt vmcnt(4)" ::: "memory");   // tile 0 ready; tile 1 in flight
  __builtin_amdgcn_s_barrier();

  // peeled t=0: stage tile 2; QK(0); exp2+PBUILD; no PV yet
  STAGE(2)
  __builtin_amdgcn_s_setprio(1);
  QK(0)
  __builtin_amdgcn_s_setprio(0);
  SOFTEXP
  PBUILD
  asm volatile("s_waitcnt vmcnt(4)" ::: "memory");   // tile 1 ready; tile 2 in flight
  __builtin_amdgcn_s_barrier();

  // main: t = 1..28 in 7 unrolled groups of 4 (KB=t&3, VR=(t-1)&3, SW=(t+2)&3)
  for (int m = 0; m < 7; ++m) {
    ITER(1, 0, 3)
    ITER(2, 1, 0)
    ITER(3, 2, 1)
    ITER(0, 3, 2)
  }
  ITER(1, 0, 3)        // t=29 (stages tile 31 -> buf 3)
  ITER_DRAIN(2, 1)     // t=30 (drain: tile 31 complete)
  ITER_LAST(3, 2)      // t=31

  // epilogue: PV of tile 31 (P in pB, V in Vl[3])
  __builtin_amdgcn_s_setprio(1);
  PVSTEP(3)
  __builtin_amdgcn_s_setprio(0);

#undef STAGE
#undef QK
#undef SOFTEXP
#undef PBUILD
#undef PVSTEP
#undef ITER
#undef ITER_DRAIN
#undef ITER_LAST

  // ---- normalize + store O^T (lane owns q = q0+(l&31); d = (r&3)+8(r>>2)+4hh+32db)
  {
    float inv = 1.0f / oaccE[0];
    int q = q0 + (l & 31);
    unsigned short* op = Ob + (long)(b * SEQ + q) * HID + h * HDIM;
#pragma unroll
    for (int db = 0; db < 2; ++db)
#pragma unroll
      for (int a = 0; a < 4; ++a) {
        int d = 8 * a + 4 * hh + 32 * db;
        unsigned int lo = pk(oacc[db][4 * a + 0] * inv, oacc[db][4 * a + 1] * inv);
        unsigned int hi2 = pk(oacc[db][4 * a + 2] * inv, oacc[db][4 * a + 3] * inv);
        uint2 uv; uv.x = lo; uv.y = hi2;
        *reinterpret_cast<uint2*>(op + d) = uv;
      }
  }
}

// ---------------- output projection (3-buf counted vmcnt, 128x64 tile): fp32 out ----------------
__global__ __launch_bounds__(256) void gemm_o(
    const unsigned short* __restrict__ A,
    const unsigned short* __restrict__ W,
    const float* __restrict__ bias,
    float* __restrict__ Out)
{
  __shared__ unsigned short Al[3][128 * 32];
  __shared__ unsigned short Bl[3][64 * 32];
  const int tm = blockIdx.x, tn = blockIdx.y;
  const int t = threadIdx.x, w = t >> 6, l = t & 63;
  const int wm = w >> 1, wn = w & 1;

  f32x4 acc[4][2] = {};
  const int arow0 = tm * 128, brow0 = tn * 64;
  const int s0 = w * 2, s1 = w * 2 + 1;
  const int r0 = s0 * 16 + (l >> 2), r1 = s1 * 16 + (l >> 2);
  const int rb = w * 16 + (l >> 2);
  const int kc = (l & 3) * 8;

#define GSTAGE(buf, k0)                                                       \
  {                                                                           \
    gload16(A + (long)(arow0 + r0) * HID + (k0) + kc, Al[buf] + s0 * 512);    \
    gload16(A + (long)(arow0 + r1) * HID + (k0) + kc, Al[buf] + s1 * 512);    \
    gload16(W + (long)(brow0 + rb) * HID + (k0) + kc, Bl[buf] + w * 512);     \
  }

  GSTAGE(0, 0)
  GSTAGE(1, 32)
  asm volatile("s_waitcnt vmcnt(3)" ::: "memory");
  __builtin_amdgcn_s_barrier();
  int cur = 0, stg = 2;
  for (int k0 = 0; k0 < HID; k0 += 32) {
    if (k0 + 64 < HID) GSTAGE(stg, k0 + 64)
    bf16x8 af[4], bfr[2];
#pragma unroll
    for (int fm = 0; fm < 4; ++fm)
      af[fm] = *reinterpret_cast<const bf16x8*>(Al[cur] + (wm * 64 + fm * 16 + (l & 15)) * 32 + (l >> 4) * 8);
#pragma unroll
    for (int fn = 0; fn < 2; ++fn)
      bfr[fn] = *reinterpret_cast<const bf16x8*>(Bl[cur] + (wn * 32 + fn * 16 + (l & 15)) * 32 + (l >> 4) * 8);
    __builtin_amdgcn_s_setprio(1);
#pragma unroll
    for (int fm = 0; fm < 4; ++fm)
#pragma unroll
      for (int fn = 0; fn < 2; ++fn)
        acc[fm][fn] = __builtin_amdgcn_mfma_f32_16x16x32_bf16(af[fm], bfr[fn], acc[fm][fn], 0, 0, 0);
    __builtin_amdgcn_s_setprio(0);
    if (k0 + 64 < HID) {
      asm volatile("s_waitcnt vmcnt(3)" ::: "memory");
    } else {
      asm volatile("s_waitcnt vmcnt(0)" ::: "memory");
    }
    __builtin_amdgcn_s_barrier();
    cur = (cur == 2) ? 0 : cur + 1;
    stg = (stg == 2) ? 0 : stg + 1;
  }
#undef GSTAGE

  const int colb = brow0 + wn * 32;
  float bsv[2];
#pragma unroll
  for (int fn = 0; fn < 2; ++fn) bsv[fn] = bias[colb + fn * 16 + (l & 15)];
#pragma unroll
  for (int fm = 0; fm < 4; ++fm)
#pragma unroll
    for (int r = 0; r < 4; ++r) {
      int grow = arow0 + wm * 64 + fm * 16 + (l >> 4) * 4 + r;
#pragma unroll
      for (int fn = 0; fn < 2; ++fn)
        Out[(long)grow * HID + colb + fn * 16 + (l & 15)] = acc[fm][fn][r] + bsv[fn];
    }
}

extern "C" void kernel_launch(void* const* d_in, const int* in_sizes, int n_in,
                              void* d_out, int out_size, void* d_ws, size_t ws_size,
                              hipStream_t stream) {
  const float* x  = (const float*)d_in[0];
  const float* qw = (const float*)d_in[1];
  const float* qb = (const float*)d_in[2];
  const float* kw = (const float*)d_in[3];
  const float* kb = (const float*)d_in[4];
  const float* vw = (const float*)d_in[5];
  const float* vb = (const float*)d_in[6];
  const float* ow = (const float*)d_in[7];
  const float* ob = (const float*)d_in[8];
  float* out = (float*)d_out;

  char* p = (char*)d_ws;
  unsigned short* xb  = (unsigned short*)p; p += (size_t)NTOK * HID * 2;
  unsigned short* wqb = (unsigned short*)p; p += (size_t)HID * HID * 2;
  unsigned short* wkb = (unsigned short*)p; p += (size_t)HID * HID * 2;
  unsigned short* wvb = (unsigned short*)p; p += (size_t)HID * HID * 2;
  unsigned short* wob = (unsigned short*)p; p += (size_t)HID * HID * 2;
  unsigned short* Qb  = (unsigned short*)p; p += (size_t)NTOK * HID * 2;
  unsigned short* Kb  = (unsigned short*)p; p += (size_t)NTOK * HID * 2;
  unsigned short* VTb = (unsigned short*)p; p += (size_t)NTOK * HID * 2;
  float* ct = (float*)p; p += (size_t)SEQ * 32 * 4;
  float* st = (float*)p; p += (size_t)SEQ * 32 * 4;
  unsigned short* Ab  = xb;   // xb dead after gemm_qkv; reuse for attn output

  const int XN = NTOK * HID / 8, WN = HID * HID / 8;
  const int prep_threads = XN + 4 * WN + SEQ * 32;
  prep<<<dim3((prep_threads + 255) / 256), 256, 0, stream>>>(
      x, qw, kw, vw, ow, xb, wqb, wkb, wvb, wob, ct, st);

  gemm_qkv<<<dim3(NTOK / 128, HID / 128, 3), 256, 0, stream>>>(
      xb, wqb, wkb, wvb, qb, kb, vb, ct, st, Qb, Kb, VTb);

  attn<<<dim3(BATCH * NHEADS, SEQ / 128), 256, 0, stream>>>(Qb, Kb, VTb, Ab);

  gemm_o<<<dim3(NTOK / 128, HID / 64), 256, 0, stream>>>(Ab, wob, ob, out);
}